// Round 1
// baseline (565.456 us; speedup 1.0000x reference)
//
#include <hip/hip_runtime.h>

#define N_NODES 50000
#define N_EDGES 800000
#define IN_F    128
#define HID_F   64
#define OUT_F   40

// ---------------- degree / norm ----------------

__global__ __launch_bounds__(256) void k_init_deg(float* __restrict__ deg) {
    int i = blockIdx.x * 256 + threadIdx.x;
    if (i < N_NODES) deg[i] = 1.0f;   // self-loop
}

__global__ __launch_bounds__(256) void k_deg_accum(const int* __restrict__ ei,
                                                   float* __restrict__ deg) {
    int e = blockIdx.x * 256 + threadIdx.x;
    if (e < N_EDGES) atomicAdd(&deg[ei[N_EDGES + e]], 1.0f);
}

__global__ __launch_bounds__(256) void k_dinv(float* __restrict__ deg) {
    int i = blockIdx.x * 256 + threadIdx.x;
    if (i < N_NODES) deg[i] = rsqrtf(deg[i]);   // deg >= 1 always
}

// ---------------- GEMM1: h1[N,64] = x[N,128] @ W1[128,64] ----------------
// block = 256 threads, 32 rows per block. W1 fully in LDS (32 KB),
// x tile padded to stride 129 to break bank conflicts.

__global__ __launch_bounds__(256) void k_gemm1(const float* __restrict__ x,
                                               const float* __restrict__ W1,
                                               float* __restrict__ h1) {
    __shared__ float sW[IN_F][HID_F];    // 32768 B
    __shared__ float sX[32][IN_F + 1];   // 16512 B
    int t = threadIdx.x;
    for (int i = t; i < IN_F * HID_F; i += 256)
        sW[i >> 6][i & 63] = W1[i];
    int row0 = blockIdx.x * 32;
    // 32 rows x 32 float4 = 1024 vector loads
    for (int i = t; i < 32 * 32; i += 256) {
        int r  = i >> 5;
        int c4 = i & 31;
        int gr = row0 + r;
        float4 v = make_float4(0.f, 0.f, 0.f, 0.f);
        if (gr < N_NODES) v = ((const float4*)x)[gr * 32 + c4];
        sX[r][c4 * 4 + 0] = v.x;
        sX[r][c4 * 4 + 1] = v.y;
        sX[r][c4 * 4 + 2] = v.z;
        sX[r][c4 * 4 + 3] = v.w;
    }
    __syncthreads();
    int c  = t & 63;       // output column (lane)
    int rg = t >> 6;       // row group 0..3 (wave id)
    float acc[8];
#pragma unroll
    for (int j = 0; j < 8; ++j) acc[j] = 0.f;
#pragma unroll 4
    for (int k = 0; k < IN_F; ++k) {
        float w = sW[k][c];
#pragma unroll
        for (int j = 0; j < 8; ++j)
            acc[j] += sX[rg * 8 + j][k] * w;   // broadcast read across lanes
    }
#pragma unroll
    for (int j = 0; j < 8; ++j) {
        int gr = row0 + rg * 8 + j;
        if (gr < N_NODES) h1[gr * HID_F + c] = acc[j];
    }
}

// ---------------- layer-1 aggregation ----------------
// init: agg1 = b1 + self_loop term; then atomic scatter over edges.

__global__ __launch_bounds__(256) void k_init_agg1(const float* __restrict__ h1,
                                                   const float* __restrict__ dinv,
                                                   const float* __restrict__ b1,
                                                   float* __restrict__ agg1) {
    int i = blockIdx.x * 256 + threadIdx.x;
    if (i < N_NODES * HID_F) {
        int row = i >> 6, c = i & 63;
        float di = dinv[row];
        agg1[i] = b1[c] + h1[i] * di * di;
    }
}

__global__ __launch_bounds__(256) void k_spmm1(const int* __restrict__ ei,
                                               const float* __restrict__ dinv,
                                               const float* __restrict__ h1,
                                               float* __restrict__ agg1) {
    int lane = threadIdx.x & 63;
    int e = blockIdx.x * 4 + (threadIdx.x >> 6);
    if (e >= N_EDGES) return;
    int s = ei[e];
    int d = ei[N_EDGES + e];
    float nrm = dinv[s] * dinv[d];
    atomicAdd(&agg1[d * HID_F + lane], h1[s * HID_F + lane] * nrm);
}

// ---------------- BN statistics ----------------

__global__ void k_zero_stats(float* __restrict__ st) {
    int i = threadIdx.x;
    if (i < 2 * HID_F) st[i] = 0.f;
}

__global__ __launch_bounds__(256) void k_bn_reduce(const float* __restrict__ agg1,
                                                   float* __restrict__ st) {
    int c    = threadIdx.x & 63;
    int rloc = threadIdx.x >> 6;
    float s = 0.f, s2 = 0.f;
    for (int r = blockIdx.x * 4 + rloc; r < N_NODES; r += gridDim.x * 4) {
        float v = agg1[r * HID_F + c];
        s  += v;
        s2 += v * v;
    }
    __shared__ float ls[4][HID_F], ls2[4][HID_F];
    ls[rloc][c]  = s;
    ls2[rloc][c] = s2;
    __syncthreads();
    if (rloc == 0) {
        s  = ls[0][c] + ls[1][c] + ls[2][c] + ls[3][c];
        s2 = ls2[0][c] + ls2[1][c] + ls2[2][c] + ls2[3][c];
        atomicAdd(&st[c], s);
        atomicAdd(&st[HID_F + c], s2);
    }
}

// ---------------- GEMM2 fused with BN + ReLU ----------------
// one thread per row: h2[row,0:40] = relu(bn(agg1[row,:])) @ W2

__global__ __launch_bounds__(256) void k_gemm2(const float* __restrict__ agg1,
                                               const float* __restrict__ st,
                                               const float* __restrict__ gamma,
                                               const float* __restrict__ beta,
                                               const float* __restrict__ W2,
                                               float* __restrict__ h2) {
    __shared__ float sW[HID_F][OUT_F];   // 10240 B
    __shared__ float sScale[HID_F], sShift[HID_F];
    int t = threadIdx.x;
    for (int i = t; i < HID_F * OUT_F; i += 256)
        sW[i / OUT_F][i % OUT_F] = W2[i];
    if (t < HID_F) {
        float mean = st[t] * (1.0f / N_NODES);
        float var  = st[HID_F + t] * (1.0f / N_NODES) - mean * mean;
        float inv  = rsqrtf(var + 1e-5f);
        float g    = gamma[t];
        sScale[t]  = g * inv;
        sShift[t]  = beta[t] - g * inv * mean;
    }
    __syncthreads();
    int row = blockIdx.x * 256 + t;
    if (row >= N_NODES) return;
    float acc[OUT_F];
#pragma unroll
    for (int c = 0; c < OUT_F; ++c) acc[c] = 0.f;
    const float* arow = agg1 + (size_t)row * HID_F;
#pragma unroll 4
    for (int k = 0; k < HID_F; ++k) {
        float v = fmaxf(arow[k] * sScale[k] + sShift[k], 0.f);
#pragma unroll
        for (int c = 0; c < OUT_F; ++c) acc[c] += v * sW[k][c];
    }
    float* orow = h2 + (size_t)row * OUT_F;
#pragma unroll
    for (int c = 0; c < OUT_F; ++c) orow[c] = acc[c];
}

// ---------------- layer-2 aggregation (into d_out, fp32) ----------------

__global__ __launch_bounds__(256) void k_init_out(const float* __restrict__ h2,
                                                  const float* __restrict__ dinv,
                                                  const float* __restrict__ b2,
                                                  float* __restrict__ out) {
    int i = blockIdx.x * 256 + threadIdx.x;
    if (i < N_NODES * OUT_F) {
        int row = i / OUT_F;
        int c   = i - row * OUT_F;
        float di = dinv[row];
        out[i] = b2[c] + h2[i] * di * di;
    }
}

__global__ __launch_bounds__(256) void k_spmm2(const int* __restrict__ ei,
                                               const float* __restrict__ dinv,
                                               const float* __restrict__ h2,
                                               float* __restrict__ out) {
    int lane = threadIdx.x & 63;
    int e = blockIdx.x * 4 + (threadIdx.x >> 6);
    if (e >= N_EDGES || lane >= OUT_F) return;
    int s = ei[e];
    int d = ei[N_EDGES + e];
    float nrm = dinv[s] * dinv[d];
    atomicAdd(&out[d * OUT_F + lane], h2[s * OUT_F + lane] * nrm);
}

// ---------------- launch ----------------

extern "C" void kernel_launch(void* const* d_in, const int* in_sizes, int n_in,
                              void* d_out, int out_size, void* d_ws, size_t ws_size,
                              hipStream_t stream) {
    const float* x     = (const float*)d_in[0];
    const int*   ei    = (const int*)d_in[1];
    const float* W1    = (const float*)d_in[2];
    const float* b1    = (const float*)d_in[3];
    const float* gamma = (const float*)d_in[4];
    const float* beta  = (const float*)d_in[5];
    const float* W2    = (const float*)d_in[6];
    const float* b2    = (const float*)d_in[7];
    float* out = (float*)d_out;

    char* ws = (char*)d_ws;
    float* dinv = (float*)(ws + 0);          //   200,000 B
    float* h1   = (float*)(ws + 200704);     // 12.8 MB
    float* agg1 = (float*)(ws + 13000704);   // 12.8 MB
    float* h2   = (float*)(ws + 25800704);   //  8.0 MB
    float* bnst = (float*)(ws + 33800704);   //    512 B

    k_init_deg<<<(N_NODES + 255) / 256, 256, 0, stream>>>(dinv);
    k_deg_accum<<<(N_EDGES + 255) / 256, 256, 0, stream>>>(ei, dinv);
    k_dinv<<<(N_NODES + 255) / 256, 256, 0, stream>>>(dinv);

    k_gemm1<<<(N_NODES + 31) / 32, 256, 0, stream>>>(x, W1, h1);

    k_init_agg1<<<(N_NODES * HID_F + 255) / 256, 256, 0, stream>>>(h1, dinv, b1, agg1);
    k_spmm1<<<(N_EDGES + 3) / 4, 256, 0, stream>>>(ei, dinv, h1, agg1);

    k_zero_stats<<<1, 128, 0, stream>>>(bnst);
    k_bn_reduce<<<512, 256, 0, stream>>>(agg1, bnst);

    k_gemm2<<<(N_NODES + 255) / 256, 256, 0, stream>>>(agg1, bnst, gamma, beta, W2, h2);

    k_init_out<<<(N_NODES * OUT_F + 255) / 256, 256, 0, stream>>>(h2, dinv, b2, out);
    k_spmm2<<<(N_EDGES + 3) / 4, 256, 0, stream>>>(ei, dinv, h2, out);
}

// Round 2
// 472.940 us; speedup vs baseline: 1.1956x; 1.1956x over previous
//
#include <hip/hip_runtime.h>

#define N_NODES 50000
#define N_EDGES 800000
#define IN_F    128
#define HID_F   64
#define OUT_F   40

// ---------------- zero counters ----------------

__global__ __launch_bounds__(256) void k_zero(int* __restrict__ cnt,
                                              float* __restrict__ st) {
    int i = blockIdx.x * 256 + threadIdx.x;
    if (i < N_NODES) cnt[i] = 0;
    else if (i < N_NODES + 2 * HID_F) st[i - N_NODES] = 0.f;
}

// ---------------- dst histogram ----------------

__global__ __launch_bounds__(256) void k_count(const int* __restrict__ ei,
                                               int* __restrict__ cnt) {
    int e = blockIdx.x * 256 + threadIdx.x;
    if (e < N_EDGES) atomicAdd(&cnt[ei[N_EDGES + e]], 1);
}

// ---------------- exclusive scan -> rowptr, fill copy, dinv ----------------
// single block, 1024 threads, 49 elements each (1024*49 = 50176 >= 50000)

__global__ __launch_bounds__(1024) void k_scan(const int* __restrict__ cnt,
                                               int* __restrict__ rowptr,
                                               int* __restrict__ fill,
                                               float* __restrict__ dinv) {
    __shared__ int sbuf[1024];
    int t = threadIdx.x;
    int lo = t * 49;
    int hi = lo + 49; if (hi > N_NODES) hi = N_NODES;
    int s = 0;
    for (int i = lo; i < hi; ++i) s += cnt[i];
    sbuf[t] = s;
    __syncthreads();
    for (int off = 1; off < 1024; off <<= 1) {
        int v = (t >= off) ? sbuf[t - off] : 0;
        __syncthreads();
        sbuf[t] += v;
        __syncthreads();
    }
    int run = sbuf[t] - s;   // exclusive prefix of this thread's chunk
    for (int i = lo; i < hi; ++i) {
        rowptr[i] = run;
        fill[i]   = run;
        int c = cnt[i];
        dinv[i] = rsqrtf((float)c + 1.0f);   // + self-loop
        run += c;
    }
    if (t == 0) rowptr[N_NODES] = N_EDGES;
}

// ---------------- scatter edges into dst-sorted order ----------------

__global__ __launch_bounds__(256) void k_scatter(const int* __restrict__ ei,
                                                 int* __restrict__ fill,
                                                 int* __restrict__ ssrc) {
    int e = blockIdx.x * 256 + threadIdx.x;
    if (e < N_EDGES) {
        int d = ei[N_EDGES + e];
        int pos = atomicAdd(&fill[d], 1);
        ssrc[pos] = ei[e];
    }
}

// ---------------- GEMM1: h1s[N,64] = (x[N,128] @ W1[128,64]) * dinv ----------------

__global__ __launch_bounds__(256) void k_gemm1(const float* __restrict__ x,
                                               const float* __restrict__ W1,
                                               const float* __restrict__ dinv,
                                               float* __restrict__ h1s) {
    __shared__ float sW[IN_F][HID_F];    // 32768 B
    __shared__ float sX[32][IN_F + 1];   // 16512 B
    int t = threadIdx.x;
    for (int i = t; i < IN_F * HID_F; i += 256)
        sW[i >> 6][i & 63] = W1[i];
    int row0 = blockIdx.x * 32;
    for (int i = t; i < 32 * 32; i += 256) {
        int r  = i >> 5;
        int c4 = i & 31;
        int gr = row0 + r;
        float4 v = make_float4(0.f, 0.f, 0.f, 0.f);
        if (gr < N_NODES) v = ((const float4*)x)[gr * 32 + c4];
        sX[r][c4 * 4 + 0] = v.x;
        sX[r][c4 * 4 + 1] = v.y;
        sX[r][c4 * 4 + 2] = v.z;
        sX[r][c4 * 4 + 3] = v.w;
    }
    __syncthreads();
    int c  = t & 63;
    int rg = t >> 6;
    float acc[8];
#pragma unroll
    for (int j = 0; j < 8; ++j) acc[j] = 0.f;
#pragma unroll 4
    for (int k = 0; k < IN_F; ++k) {
        float w = sW[k][c];
#pragma unroll
        for (int j = 0; j < 8; ++j)
            acc[j] += sX[rg * 8 + j][k] * w;
    }
#pragma unroll
    for (int j = 0; j < 8; ++j) {
        int gr = row0 + rg * 8 + j;
        if (gr < N_NODES) h1s[gr * HID_F + c] = acc[j] * dinv[gr];
    }
}

// ---------------- layer-1 aggregation: gather, no atomics ----------------
// wave per node, lane = feature. agg1[d] = dinv[d]*(sum_src h1s[s] + h1s[d]) + b1

__global__ __launch_bounds__(256) void k_agg1(const int* __restrict__ rowptr,
                                              const int* __restrict__ ssrc,
                                              const float* __restrict__ dinv,
                                              const float* __restrict__ h1s,
                                              const float* __restrict__ b1,
                                              float* __restrict__ agg1) {
    int lane = threadIdx.x & 63;
    int d = blockIdx.x * 4 + (threadIdx.x >> 6);
    if (d >= N_NODES) return;
    int base = rowptr[d];
    int end  = rowptr[d + 1];
    float acc = h1s[d * HID_F + lane];   // self-loop (pre-scaled by dinv[d])
    for (int j0 = base; j0 < end; j0 += 64) {
        int idx = j0 + lane;
        int sl = (idx < end) ? ssrc[idx] : 0;   // coalesced batch of src ids
        int m = end - j0; if (m > 64) m = 64;
#pragma unroll 4
        for (int j = 0; j < m; ++j) {
            int s = __shfl(sl, j);
            acc += h1s[s * HID_F + lane];
        }
    }
    agg1[d * HID_F + lane] = acc * dinv[d] + b1[lane];
}

// ---------------- BN statistics ----------------

__global__ __launch_bounds__(256) void k_bn_reduce(const float* __restrict__ agg1,
                                                   float* __restrict__ st) {
    int c    = threadIdx.x & 63;
    int rloc = threadIdx.x >> 6;
    float s = 0.f, s2 = 0.f;
    for (int r = blockIdx.x * 4 + rloc; r < N_NODES; r += gridDim.x * 4) {
        float v = agg1[r * HID_F + c];
        s  += v;
        s2 += v * v;
    }
    __shared__ float ls[4][HID_F], ls2[4][HID_F];
    ls[rloc][c]  = s;
    ls2[rloc][c] = s2;
    __syncthreads();
    if (rloc == 0) {
        s  = ls[0][c] + ls[1][c] + ls[2][c] + ls[3][c];
        s2 = ls2[0][c] + ls2[1][c] + ls2[2][c] + ls2[3][c];
        atomicAdd(&st[c], s);
        atomicAdd(&st[HID_F + c], s2);
    }
}

// ---------------- GEMM2 fused BN + ReLU, epilogue *dinv ----------------

__global__ __launch_bounds__(256) void k_gemm2(const float* __restrict__ agg1,
                                               const float* __restrict__ st,
                                               const float* __restrict__ gamma,
                                               const float* __restrict__ beta,
                                               const float* __restrict__ W2,
                                               const float* __restrict__ dinv,
                                               float* __restrict__ h2s) {
    __shared__ float sW[HID_F][OUT_F];
    __shared__ float sScale[HID_F], sShift[HID_F];
    int t = threadIdx.x;
    for (int i = t; i < HID_F * OUT_F; i += 256)
        sW[i / OUT_F][i % OUT_F] = W2[i];
    if (t < HID_F) {
        float mean = st[t] * (1.0f / N_NODES);
        float var  = st[HID_F + t] * (1.0f / N_NODES) - mean * mean;
        float inv  = rsqrtf(var + 1e-5f);
        float g    = gamma[t];
        sScale[t]  = g * inv;
        sShift[t]  = beta[t] - g * inv * mean;
    }
    __syncthreads();
    int row = blockIdx.x * 256 + t;
    if (row >= N_NODES) return;
    float acc[OUT_F];
#pragma unroll
    for (int c = 0; c < OUT_F; ++c) acc[c] = 0.f;
    const float* arow = agg1 + (size_t)row * HID_F;
#pragma unroll 4
    for (int k = 0; k < HID_F; ++k) {
        float v = fmaxf(arow[k] * sScale[k] + sShift[k], 0.f);
#pragma unroll
        for (int c = 0; c < OUT_F; ++c) acc[c] += v * sW[k][c];
    }
    float di = dinv[row];
    float* orow = h2s + (size_t)row * OUT_F;
#pragma unroll
    for (int c = 0; c < OUT_F; ++c) orow[c] = acc[c] * di;
}

// ---------------- layer-2 aggregation: gather into d_out ----------------

__global__ __launch_bounds__(256) void k_agg2(const int* __restrict__ rowptr,
                                              const int* __restrict__ ssrc,
                                              const float* __restrict__ dinv,
                                              const float* __restrict__ h2s,
                                              const float* __restrict__ b2,
                                              float* __restrict__ out) {
    int lane = threadIdx.x & 63;
    int d = blockIdx.x * 4 + (threadIdx.x >> 6);
    if (d >= N_NODES) return;
    int base = rowptr[d];
    int end  = rowptr[d + 1];
    // lanes >= OUT_F read harmlessly within the buffer; masked at write
    float acc = h2s[d * OUT_F + ((lane < OUT_F) ? lane : 0)];
    for (int j0 = base; j0 < end; j0 += 64) {
        int idx = j0 + lane;
        int sl = (idx < end) ? ssrc[idx] : 0;
        int m = end - j0; if (m > 64) m = 64;
#pragma unroll 4
        for (int j = 0; j < m; ++j) {
            int s = __shfl(sl, j);
            acc += h2s[s * OUT_F + ((lane < OUT_F) ? lane : 0)];
        }
    }
    if (lane < OUT_F)
        out[d * OUT_F + lane] = acc * dinv[d] + b2[lane];
}

// ---------------- launch ----------------

extern "C" void kernel_launch(void* const* d_in, const int* in_sizes, int n_in,
                              void* d_out, int out_size, void* d_ws, size_t ws_size,
                              hipStream_t stream) {
    const float* x     = (const float*)d_in[0];
    const int*   ei    = (const int*)d_in[1];
    const float* W1    = (const float*)d_in[2];
    const float* b1    = (const float*)d_in[3];
    const float* gamma = (const float*)d_in[4];
    const float* beta  = (const float*)d_in[5];
    const float* W2    = (const float*)d_in[6];
    const float* b2    = (const float*)d_in[7];
    float* out = (float*)d_out;

    char* ws = (char*)d_ws;
    int*   cnt    = (int*)  (ws + 0);          //   200,704 B
    int*   rowptr = (int*)  (ws + 200704);     //   200,704 B (50001 ints)
    int*   fill   = (int*)  (ws + 401408);     //   200,704 B
    float* dinv   = (float*)(ws + 602112);     //   200,704 B
    int*   ssrc   = (int*)  (ws + 802816);     // 3,200,512 B
    float* h1s    = (float*)(ws + 4003328);    // 12,800,512 B
    float* h2s    = (float*)(ws + 4003328);    //   (overlays h1s; h1s dead after k_agg1)
    float* agg1   = (float*)(ws + 16803840);   // 12,800,512 B
    float* bnst   = (float*)(ws + 29604352);   //       512 B
    // total: ~29.6 MB

    k_zero<<<(N_NODES + 2 * HID_F + 255) / 256, 256, 0, stream>>>(cnt, bnst);
    k_count<<<(N_EDGES + 255) / 256, 256, 0, stream>>>(ei, cnt);
    k_scan<<<1, 1024, 0, stream>>>(cnt, rowptr, fill, dinv);
    k_scatter<<<(N_EDGES + 255) / 256, 256, 0, stream>>>(ei, fill, ssrc);

    k_gemm1<<<(N_NODES + 31) / 32, 256, 0, stream>>>(x, W1, dinv, h1s);
    k_agg1<<<(N_NODES + 3) / 4, 256, 0, stream>>>(rowptr, ssrc, dinv, h1s, b1, agg1);

    k_bn_reduce<<<512, 256, 0, stream>>>(agg1, bnst);
    k_gemm2<<<(N_NODES + 255) / 256, 256, 0, stream>>>(agg1, bnst, gamma, beta, W2, dinv, h2s);
    k_agg2<<<(N_NODES + 3) / 4, 256, 0, stream>>>(rowptr, ssrc, dinv, h2s, b2, out);
}

// Round 3
// 360.695 us; speedup vs baseline: 1.5677x; 1.3112x over previous
//
#include <hip/hip_runtime.h>

#define N_NODES 50000
#define N_EDGES 800000
#define IN_F    128
#define HID_F   64
#define OUT_F   40
#define NB_SCAN ((N_NODES + 255) / 256)   // 196

// ---------------- zero counters ----------------

__global__ __launch_bounds__(256) void k_zero(int* __restrict__ cnt,
                                              float* __restrict__ st) {
    int i = blockIdx.x * 256 + threadIdx.x;
    if (i < N_NODES) cnt[i] = 0;
    else if (i < N_NODES + 2 * HID_F) st[i - N_NODES] = 0.f;
}

// ---------------- dst histogram ----------------

__global__ __launch_bounds__(256) void k_count(const int* __restrict__ ei,
                                               int* __restrict__ cnt) {
    int e = blockIdx.x * 256 + threadIdx.x;
    if (e < N_EDGES) atomicAdd(&cnt[ei[N_EDGES + e]], 1);
}

// ---------------- 3-phase parallel exclusive scan ----------------

__global__ __launch_bounds__(256) void k_scan1(const int* __restrict__ cnt,
                                               int* __restrict__ bsum) {
    int t = threadIdx.x;
    int i = blockIdx.x * 256 + t;
    int v = (i < N_NODES) ? cnt[i] : 0;
    // wave reduce
#pragma unroll
    for (int off = 32; off > 0; off >>= 1) v += __shfl_down(v, off);
    __shared__ int ws[4];
    if ((t & 63) == 0) ws[t >> 6] = v;
    __syncthreads();
    if (t == 0) bsum[blockIdx.x] = ws[0] + ws[1] + ws[2] + ws[3];
}

__global__ __launch_bounds__(256) void k_scan2(const int* __restrict__ bsum,
                                               int* __restrict__ boff) {
    __shared__ int s[256];
    int t = threadIdx.x;
    int v = (t < NB_SCAN) ? bsum[t] : 0;
    s[t] = v;
    __syncthreads();
#pragma unroll
    for (int off = 1; off < 256; off <<= 1) {
        int u = (t >= off) ? s[t - off] : 0;
        __syncthreads();
        s[t] += u;
        __syncthreads();
    }
    if (t < NB_SCAN) boff[t] = s[t] - v;   // exclusive
}

__global__ __launch_bounds__(256) void k_scan3(const int* __restrict__ cnt,
                                               const int* __restrict__ boff,
                                               int* __restrict__ rowptr,
                                               int* __restrict__ fill,
                                               float* __restrict__ dinv) {
    __shared__ int s[256];
    int t = threadIdx.x;
    int i = blockIdx.x * 256 + t;
    int v = (i < N_NODES) ? cnt[i] : 0;
    s[t] = v;
    __syncthreads();
#pragma unroll
    for (int off = 1; off < 256; off <<= 1) {
        int u = (t >= off) ? s[t - off] : 0;
        __syncthreads();
        s[t] += u;
        __syncthreads();
    }
    if (i < N_NODES) {
        int ex = s[t] - v + boff[blockIdx.x];
        rowptr[i] = ex;
        fill[i]   = ex;
        dinv[i]   = rsqrtf((float)v + 1.0f);   // + self-loop
    }
    if (i == 0) rowptr[N_NODES] = N_EDGES;
}

// ---------------- scatter edges into dst-sorted order ----------------

__global__ __launch_bounds__(256) void k_scatter(const int* __restrict__ ei,
                                                 int* __restrict__ fill,
                                                 int* __restrict__ ssrc) {
    int e = blockIdx.x * 256 + threadIdx.x;
    if (e < N_EDGES) {
        int d = ei[N_EDGES + e];
        int pos = atomicAdd(&fill[d], 1);
        ssrc[pos] = ei[e];
    }
}

// ---------------- GEMM1: h1s[N,64] = (x[N,128] @ W1[128,64]) * dinv ----------------

__global__ __launch_bounds__(256) void k_gemm1(const float* __restrict__ x,
                                               const float* __restrict__ W1,
                                               const float* __restrict__ dinv,
                                               float* __restrict__ h1s) {
    __shared__ float sW[IN_F][HID_F];    // 32768 B
    __shared__ float sX[32][IN_F + 1];   // 16512 B
    int t = threadIdx.x;
    for (int i = t; i < IN_F * HID_F; i += 256)
        sW[i >> 6][i & 63] = W1[i];
    int row0 = blockIdx.x * 32;
    for (int i = t; i < 32 * 32; i += 256) {
        int r  = i >> 5;
        int c4 = i & 31;
        int gr = row0 + r;
        float4 v = make_float4(0.f, 0.f, 0.f, 0.f);
        if (gr < N_NODES) v = ((const float4*)x)[gr * 32 + c4];
        sX[r][c4 * 4 + 0] = v.x;
        sX[r][c4 * 4 + 1] = v.y;
        sX[r][c4 * 4 + 2] = v.z;
        sX[r][c4 * 4 + 3] = v.w;
    }
    __syncthreads();
    int c  = t & 63;
    int rg = t >> 6;
    float acc[8];
#pragma unroll
    for (int j = 0; j < 8; ++j) acc[j] = 0.f;
#pragma unroll 4
    for (int k = 0; k < IN_F; ++k) {
        float w = sW[k][c];
#pragma unroll
        for (int j = 0; j < 8; ++j)
            acc[j] += sX[rg * 8 + j][k] * w;
    }
#pragma unroll
    for (int j = 0; j < 8; ++j) {
        int gr = row0 + rg * 8 + j;
        if (gr < N_NODES) h1s[gr * HID_F + c] = acc[j] * dinv[gr];
    }
}

// ---------------- layer-1 aggregation: gather, no atomics ----------------

__global__ __launch_bounds__(256) void k_agg1(const int* __restrict__ rowptr,
                                              const int* __restrict__ ssrc,
                                              const float* __restrict__ dinv,
                                              const float* __restrict__ h1s,
                                              const float* __restrict__ b1,
                                              float* __restrict__ agg1) {
    int lane = threadIdx.x & 63;
    int d = blockIdx.x * 4 + (threadIdx.x >> 6);
    if (d >= N_NODES) return;
    int base = rowptr[d];
    int end  = rowptr[d + 1];
    float acc = h1s[d * HID_F + lane];   // self-loop (pre-scaled by dinv[d])
    for (int j0 = base; j0 < end; j0 += 64) {
        int idx = j0 + lane;
        int sl = (idx < end) ? ssrc[idx] : 0;   // coalesced batch of src ids
        int m = end - j0; if (m > 64) m = 64;
#pragma unroll 4
        for (int j = 0; j < m; ++j) {
            int s = __shfl(sl, j);
            acc += h1s[s * HID_F + lane];
        }
    }
    agg1[d * HID_F + lane] = acc * dinv[d] + b1[lane];
}

// ---------------- BN statistics ----------------

__global__ __launch_bounds__(256) void k_bn_reduce(const float* __restrict__ agg1,
                                                   float* __restrict__ st) {
    int c    = threadIdx.x & 63;
    int rloc = threadIdx.x >> 6;
    float s = 0.f, s2 = 0.f;
    for (int r = blockIdx.x * 4 + rloc; r < N_NODES; r += gridDim.x * 4) {
        float v = agg1[r * HID_F + c];
        s  += v;
        s2 += v * v;
    }
    __shared__ float ls[4][HID_F], ls2[4][HID_F];
    ls[rloc][c]  = s;
    ls2[rloc][c] = s2;
    __syncthreads();
    if (rloc == 0) {
        s  = ls[0][c] + ls[1][c] + ls[2][c] + ls[3][c];
        s2 = ls2[0][c] + ls2[1][c] + ls2[2][c] + ls2[3][c];
        atomicAdd(&st[c], s);
        atomicAdd(&st[HID_F + c], s2);
    }
}

// ---------------- GEMM2 fused BN + ReLU, epilogue *dinv ----------------

__global__ __launch_bounds__(256) void k_gemm2(const float* __restrict__ agg1,
                                               const float* __restrict__ st,
                                               const float* __restrict__ gamma,
                                               const float* __restrict__ beta,
                                               const float* __restrict__ W2,
                                               const float* __restrict__ dinv,
                                               float* __restrict__ h2s) {
    __shared__ float sW[HID_F][OUT_F];
    __shared__ float sScale[HID_F], sShift[HID_F];
    int t = threadIdx.x;
    for (int i = t; i < HID_F * OUT_F; i += 256)
        sW[i / OUT_F][i % OUT_F] = W2[i];
    if (t < HID_F) {
        float mean = st[t] * (1.0f / N_NODES);
        float var  = st[HID_F + t] * (1.0f / N_NODES) - mean * mean;
        float inv  = rsqrtf(var + 1e-5f);
        float g    = gamma[t];
        sScale[t]  = g * inv;
        sShift[t]  = beta[t] - g * inv * mean;
    }
    __syncthreads();
    int row = blockIdx.x * 256 + t;
    if (row >= N_NODES) return;
    float acc[OUT_F];
#pragma unroll
    for (int c = 0; c < OUT_F; ++c) acc[c] = 0.f;
    const float* arow = agg1 + (size_t)row * HID_F;
#pragma unroll 4
    for (int k = 0; k < HID_F; ++k) {
        float v = fmaxf(arow[k] * sScale[k] + sShift[k], 0.f);
#pragma unroll
        for (int c = 0; c < OUT_F; ++c) acc[c] += v * sW[k][c];
    }
    float di = dinv[row];
    float* orow = h2s + (size_t)row * OUT_F;
#pragma unroll
    for (int c = 0; c < OUT_F; ++c) orow[c] = acc[c] * di;
}

// ---------------- layer-2 aggregation: gather into d_out ----------------

__global__ __launch_bounds__(256) void k_agg2(const int* __restrict__ rowptr,
                                              const int* __restrict__ ssrc,
                                              const float* __restrict__ dinv,
                                              const float* __restrict__ h2s,
                                              const float* __restrict__ b2,
                                              float* __restrict__ out) {
    int lane = threadIdx.x & 63;
    int d = blockIdx.x * 4 + (threadIdx.x >> 6);
    if (d >= N_NODES) return;
    int base = rowptr[d];
    int end  = rowptr[d + 1];
    int cl = (lane < OUT_F) ? lane : 0;
    float acc = h2s[d * OUT_F + cl];
    for (int j0 = base; j0 < end; j0 += 64) {
        int idx = j0 + lane;
        int sl = (idx < end) ? ssrc[idx] : 0;
        int m = end - j0; if (m > 64) m = 64;
#pragma unroll 4
        for (int j = 0; j < m; ++j) {
            int s = __shfl(sl, j);
            acc += h2s[s * OUT_F + cl];
        }
    }
    if (lane < OUT_F)
        out[d * OUT_F + lane] = acc * dinv[d] + b2[lane];
}

// ---------------- launch ----------------

extern "C" void kernel_launch(void* const* d_in, const int* in_sizes, int n_in,
                              void* d_out, int out_size, void* d_ws, size_t ws_size,
                              hipStream_t stream) {
    const float* x     = (const float*)d_in[0];
    const int*   ei    = (const int*)d_in[1];
    const float* W1    = (const float*)d_in[2];
    const float* b1    = (const float*)d_in[3];
    const float* gamma = (const float*)d_in[4];
    const float* beta  = (const float*)d_in[5];
    const float* W2    = (const float*)d_in[6];
    const float* b2    = (const float*)d_in[7];
    float* out = (float*)d_out;

    char* ws = (char*)d_ws;
    int*   cnt    = (int*)  (ws + 0);          //   200,704 B
    int*   rowptr = (int*)  (ws + 200704);     //   200,704 B (50001 ints)
    int*   fill   = (int*)  (ws + 401408);     //   200,704 B
    float* dinv   = (float*)(ws + 602112);     //   200,704 B
    int*   ssrc   = (int*)  (ws + 802816);     // 3,200,512 B
    float* h1s    = (float*)(ws + 4003328);    // 12,800,512 B
    float* h2s    = (float*)(ws + 4003328);    //   (overlays h1s; h1s dead after k_agg1)
    float* agg1   = (float*)(ws + 16803840);   // 12,800,512 B
    float* bnst   = (float*)(ws + 29604352);   //       512 B
    int*   bsum   = (int*)  (ws + 29605888);   //       784 B
    int*   boff   = (int*)  (ws + 29606912);   //       784 B
    // total: ~29.6 MB

    k_zero<<<(N_NODES + 2 * HID_F + 255) / 256, 256, 0, stream>>>(cnt, bnst);
    k_count<<<(N_EDGES + 255) / 256, 256, 0, stream>>>(ei, cnt);
    k_scan1<<<NB_SCAN, 256, 0, stream>>>(cnt, bsum);
    k_scan2<<<1, 256, 0, stream>>>(bsum, boff);
    k_scan3<<<NB_SCAN, 256, 0, stream>>>(cnt, boff, rowptr, fill, dinv);
    k_scatter<<<(N_EDGES + 255) / 256, 256, 0, stream>>>(ei, fill, ssrc);

    k_gemm1<<<(N_NODES + 31) / 32, 256, 0, stream>>>(x, W1, dinv, h1s);
    k_agg1<<<(N_NODES + 3) / 4, 256, 0, stream>>>(rowptr, ssrc, dinv, h1s, b1, agg1);

    k_bn_reduce<<<512, 256, 0, stream>>>(agg1, bnst);
    k_gemm2<<<(N_NODES + 255) / 256, 256, 0, stream>>>(agg1, bnst, gamma, beta, W2, dinv, h2s);
    k_agg2<<<(N_NODES + 3) / 4, 256, 0, stream>>>(rowptr, ssrc, dinv, h2s, b2, out);
}

// Round 4
// 345.196 us; speedup vs baseline: 1.6381x; 1.0449x over previous
//
#include <hip/hip_runtime.h>
#include <hip/hip_fp16.h>

#define N_NODES 50000
#define N_EDGES 800000
#define IN_F    128
#define HID_F   64
#define OUT_F   40
#define NB_SCAN ((N_NODES + 255) / 256)   // 196
#define NB_SC   ((N_EDGES + 255) / 256)   // 3125 scatter blocks
#define NB_G1   ((N_NODES + 31) / 32)     // 1563 gemm1 blocks

// ---------------- zero counters ----------------

__global__ __launch_bounds__(256) void k_zero(int* __restrict__ cnt,
                                              float* __restrict__ st) {
    int i = blockIdx.x * 256 + threadIdx.x;
    if (i < N_NODES) cnt[i] = 0;
    else if (i < N_NODES + 2 * HID_F) st[i - N_NODES] = 0.f;
}

// ---------------- dst histogram ----------------

__global__ __launch_bounds__(256) void k_count(const int* __restrict__ ei,
                                               int* __restrict__ cnt) {
    int e = blockIdx.x * 256 + threadIdx.x;
    if (e < N_EDGES) atomicAdd(&cnt[ei[N_EDGES + e]], 1);
}

// ---------------- 3-phase parallel exclusive scan ----------------

__global__ __launch_bounds__(256) void k_scan1(const int* __restrict__ cnt,
                                               int* __restrict__ bsum) {
    int t = threadIdx.x;
    int i = blockIdx.x * 256 + t;
    int v = (i < N_NODES) ? cnt[i] : 0;
#pragma unroll
    for (int off = 32; off > 0; off >>= 1) v += __shfl_down(v, off);
    __shared__ int ws[4];
    if ((t & 63) == 0) ws[t >> 6] = v;
    __syncthreads();
    if (t == 0) bsum[blockIdx.x] = ws[0] + ws[1] + ws[2] + ws[3];
}

__global__ __launch_bounds__(256) void k_scan2(const int* __restrict__ bsum,
                                               int* __restrict__ boff) {
    __shared__ int s[256];
    int t = threadIdx.x;
    int v = (t < NB_SCAN) ? bsum[t] : 0;
    s[t] = v;
    __syncthreads();
#pragma unroll
    for (int off = 1; off < 256; off <<= 1) {
        int u = (t >= off) ? s[t - off] : 0;
        __syncthreads();
        s[t] += u;
        __syncthreads();
    }
    if (t < NB_SCAN) boff[t] = s[t] - v;   // exclusive
}

__global__ __launch_bounds__(256) void k_scan3(const int* __restrict__ cnt,
                                               const int* __restrict__ boff,
                                               int* __restrict__ rowptr,
                                               int* __restrict__ fill,
                                               float* __restrict__ dinv) {
    __shared__ int s[256];
    int t = threadIdx.x;
    int i = blockIdx.x * 256 + t;
    int v = (i < N_NODES) ? cnt[i] : 0;
    s[t] = v;
    __syncthreads();
#pragma unroll
    for (int off = 1; off < 256; off <<= 1) {
        int u = (t >= off) ? s[t - off] : 0;
        __syncthreads();
        s[t] += u;
        __syncthreads();
    }
    if (i < N_NODES) {
        int ex = s[t] - v + boff[blockIdx.x];
        rowptr[i] = ex;
        fill[i]   = ex;
        dinv[i]   = rsqrtf((float)v + 1.0f);   // + self-loop
    }
    if (i == 0) rowptr[N_NODES] = N_EDGES;
}

// ---------------- fused: edge scatter (blocks 0..NB_SC) || GEMM1 (rest) ----
// scatter: ssrc as uint16 (ids < 65536) -> half the partial-line writebacks
// gemm1:   h1s[N,64] = (x @ W1) * dinv, stored fp16

__global__ __launch_bounds__(256) void k_fused1(const float* __restrict__ x,
                                                const float* __restrict__ W1,
                                                const float* __restrict__ dinv,
                                                __half* __restrict__ h1s,
                                                const int* __restrict__ ei,
                                                int* __restrict__ fill,
                                                unsigned short* __restrict__ ssrc) {
    int t = threadIdx.x;
    if (blockIdx.x < NB_SC) {
        int e = blockIdx.x * 256 + t;
        if (e < N_EDGES) {
            int d = ei[N_EDGES + e];
            int pos = atomicAdd(&fill[d], 1);
            ssrc[pos] = (unsigned short)ei[e];
        }
        return;
    }
    __shared__ float sW[IN_F][HID_F];    // 32768 B
    __shared__ float sX[32][IN_F + 1];   // 16512 B
    int bid = blockIdx.x - NB_SC;
    for (int i = t; i < IN_F * HID_F; i += 256)
        sW[i >> 6][i & 63] = W1[i];
    int row0 = bid * 32;
    for (int i = t; i < 32 * 32; i += 256) {
        int r  = i >> 5;
        int c4 = i & 31;
        int gr = row0 + r;
        float4 v = make_float4(0.f, 0.f, 0.f, 0.f);
        if (gr < N_NODES) v = ((const float4*)x)[gr * 32 + c4];
        sX[r][c4 * 4 + 0] = v.x;
        sX[r][c4 * 4 + 1] = v.y;
        sX[r][c4 * 4 + 2] = v.z;
        sX[r][c4 * 4 + 3] = v.w;
    }
    __syncthreads();
    int c  = t & 63;
    int rg = t >> 6;
    float acc[8];
#pragma unroll
    for (int j = 0; j < 8; ++j) acc[j] = 0.f;
#pragma unroll 4
    for (int k = 0; k < IN_F; ++k) {
        float w = sW[k][c];
#pragma unroll
        for (int j = 0; j < 8; ++j)
            acc[j] += sX[rg * 8 + j][k] * w;
    }
#pragma unroll
    for (int j = 0; j < 8; ++j) {
        int gr = row0 + rg * 8 + j;
        if (gr < N_NODES) h1s[gr * HID_F + c] = __float2half(acc[j] * dinv[gr]);
    }
}

// ---------------- layer-1 aggregation: fp16 gather, no atomics ----------------

__global__ __launch_bounds__(256) void k_agg1(const int* __restrict__ rowptr,
                                              const unsigned short* __restrict__ ssrc,
                                              const float* __restrict__ dinv,
                                              const __half* __restrict__ h1s,
                                              const float* __restrict__ b1,
                                              float* __restrict__ agg1) {
    int lane = threadIdx.x & 63;
    int d = blockIdx.x * 4 + (threadIdx.x >> 6);
    if (d >= N_NODES) return;
    int base = rowptr[d];
    int end  = rowptr[d + 1];
    float acc = __half2float(h1s[d * HID_F + lane]);   // self-loop (pre-scaled)
    for (int j0 = base; j0 < end; j0 += 64) {
        int idx = j0 + lane;
        int sl = (idx < end) ? (int)ssrc[idx] : 0;     // coalesced src-id batch
        int m = end - j0; if (m > 64) m = 64;
#pragma unroll 4
        for (int j = 0; j < m; ++j) {
            int s = __shfl(sl, j);
            acc += __half2float(h1s[s * HID_F + lane]);
        }
    }
    agg1[d * HID_F + lane] = acc * dinv[d] + b1[lane];
}

// ---------------- BN statistics ----------------

__global__ __launch_bounds__(256) void k_bn_reduce(const float* __restrict__ agg1,
                                                   float* __restrict__ st) {
    int c    = threadIdx.x & 63;
    int rloc = threadIdx.x >> 6;
    float s = 0.f, s2 = 0.f;
    for (int r = blockIdx.x * 4 + rloc; r < N_NODES; r += gridDim.x * 4) {
        float v = agg1[r * HID_F + c];
        s  += v;
        s2 += v * v;
    }
    __shared__ float ls[4][HID_F], ls2[4][HID_F];
    ls[rloc][c]  = s;
    ls2[rloc][c] = s2;
    __syncthreads();
    if (rloc == 0) {
        s  = ls[0][c] + ls[1][c] + ls[2][c] + ls[3][c];
        s2 = ls2[0][c] + ls2[1][c] + ls2[2][c] + ls2[3][c];
        atomicAdd(&st[c], s);
        atomicAdd(&st[HID_F + c], s2);
    }
}

// ---------------- GEMM2 fused BN + ReLU, epilogue *dinv, fp16 out ----------

__global__ __launch_bounds__(256) void k_gemm2(const float* __restrict__ agg1,
                                               const float* __restrict__ st,
                                               const float* __restrict__ gamma,
                                               const float* __restrict__ beta,
                                               const float* __restrict__ W2,
                                               const float* __restrict__ dinv,
                                               __half* __restrict__ h2s) {
    __shared__ float sW[HID_F][OUT_F];
    __shared__ float sScale[HID_F], sShift[HID_F];
    int t = threadIdx.x;
    for (int i = t; i < HID_F * OUT_F; i += 256)
        sW[i / OUT_F][i % OUT_F] = W2[i];
    if (t < HID_F) {
        float mean = st[t] * (1.0f / N_NODES);
        float var  = st[HID_F + t] * (1.0f / N_NODES) - mean * mean;
        float inv  = rsqrtf(var + 1e-5f);
        float g    = gamma[t];
        sScale[t]  = g * inv;
        sShift[t]  = beta[t] - g * inv * mean;
    }
    __syncthreads();
    int row = blockIdx.x * 256 + t;
    if (row >= N_NODES) return;
    float acc[OUT_F];
#pragma unroll
    for (int c = 0; c < OUT_F; ++c) acc[c] = 0.f;
    const float* arow = agg1 + (size_t)row * HID_F;
#pragma unroll 4
    for (int k = 0; k < HID_F; ++k) {
        float v = fmaxf(arow[k] * sScale[k] + sShift[k], 0.f);
#pragma unroll
        for (int c = 0; c < OUT_F; ++c) acc[c] += v * sW[k][c];
    }
    float di = dinv[row];
    __half* orow = h2s + (size_t)row * OUT_F;
#pragma unroll
    for (int c = 0; c < OUT_F; ++c) orow[c] = __float2half(acc[c] * di);
}

// ---------------- layer-2 aggregation: fp16 gather into d_out ----------------

__global__ __launch_bounds__(256) void k_agg2(const int* __restrict__ rowptr,
                                              const unsigned short* __restrict__ ssrc,
                                              const float* __restrict__ dinv,
                                              const __half* __restrict__ h2s,
                                              const float* __restrict__ b2,
                                              float* __restrict__ out) {
    int lane = threadIdx.x & 63;
    int d = blockIdx.x * 4 + (threadIdx.x >> 6);
    if (d >= N_NODES) return;
    int base = rowptr[d];
    int end  = rowptr[d + 1];
    int cl = (lane < OUT_F) ? lane : 0;
    float acc = __half2float(h2s[d * OUT_F + cl]);
    for (int j0 = base; j0 < end; j0 += 64) {
        int idx = j0 + lane;
        int sl = (idx < end) ? (int)ssrc[idx] : 0;
        int m = end - j0; if (m > 64) m = 64;
#pragma unroll 4
        for (int j = 0; j < m; ++j) {
            int s = __shfl(sl, j);
            acc += __half2float(h2s[s * OUT_F + cl]);
        }
    }
    if (lane < OUT_F)
        out[d * OUT_F + lane] = acc * dinv[d] + b2[lane];
}

// ---------------- launch ----------------

extern "C" void kernel_launch(void* const* d_in, const int* in_sizes, int n_in,
                              void* d_out, int out_size, void* d_ws, size_t ws_size,
                              hipStream_t stream) {
    const float* x     = (const float*)d_in[0];
    const int*   ei    = (const int*)d_in[1];
    const float* W1    = (const float*)d_in[2];
    const float* b1    = (const float*)d_in[3];
    const float* gamma = (const float*)d_in[4];
    const float* beta  = (const float*)d_in[5];
    const float* W2    = (const float*)d_in[6];
    const float* b2    = (const float*)d_in[7];
    float* out = (float*)d_out;

    char* ws = (char*)d_ws;
    int*            cnt    = (int*)           (ws + 0);          //   200,704 B
    int*            rowptr = (int*)           (ws + 200704);     //   200,704 B
    int*            fill   = (int*)           (ws + 401408);     //   200,704 B
    float*          dinv   = (float*)         (ws + 602112);     //   200,704 B
    unsigned short* ssrc   = (unsigned short*)(ws + 802816);     // 1,600,512 B
    __half*         h1s    = (__half*)        (ws + 2403328);    // 6,400,512 B
    __half*         h2s    = (__half*)        (ws + 8803840);    // 4,000,512 B
    float*          agg1   = (float*)         (ws + 12804352);   // 12,800,512 B
    float*          bnst   = (float*)         (ws + 25604864);   //       512 B
    int*            bsum   = (int*)           (ws + 25605888);   //       784 B
    int*            boff   = (int*)           (ws + 25606912);   //       784 B
    // total ~25.6 MB

    k_zero<<<(N_NODES + 2 * HID_F + 255) / 256, 256, 0, stream>>>(cnt, bnst);
    k_count<<<(N_EDGES + 255) / 256, 256, 0, stream>>>(ei, cnt);
    k_scan1<<<NB_SCAN, 256, 0, stream>>>(cnt, bsum);
    k_scan2<<<1, 256, 0, stream>>>(bsum, boff);
    k_scan3<<<NB_SCAN, 256, 0, stream>>>(cnt, boff, rowptr, fill, dinv);

    k_fused1<<<NB_SC + NB_G1, 256, 0, stream>>>(x, W1, dinv, h1s, ei, fill, ssrc);
    k_agg1<<<(N_NODES + 3) / 4, 256, 0, stream>>>(rowptr, ssrc, dinv, h1s, b1, agg1);

    k_bn_reduce<<<512, 256, 0, stream>>>(agg1, bnst);
    k_gemm2<<<(N_NODES + 255) / 256, 256, 0, stream>>>(agg1, bnst, gamma, beta, W2, dinv, h2s);
    k_agg2<<<(N_NODES + 3) / 4, 256, 0, stream>>>(rowptr, ssrc, dinv, h2s, b2, out);
}

// Round 5
// 288.916 us; speedup vs baseline: 1.9572x; 1.1948x over previous
//
#include <hip/hip_runtime.h>
#include <hip/hip_fp16.h>

#define N_NODES 50000
#define N_EDGES 800000
#define IN_F    128
#define HID_F   64
#define OUT_F   40

#define EPB   8192                       // edges per sort block
#define NBLK  ((N_EDGES + EPB - 1) / EPB)   // 98
#define NBK   ((N_NODES + 255) / 256)       // 196 buckets (dst >> 8)
#define CAP   6144                       // per-bucket LDS capacity (avg 4096, sd 64)
#define NB_G1 ((N_NODES + 31) / 32)      // 1563 gemm1 blocks

// ---------------- pass 1: per-block bucket histogram ----------------

__global__ __launch_bounds__(256) void k_hist(const int* __restrict__ ei,
                                              int* __restrict__ blkcnt) {
    __shared__ int h[NBK];
    int t = threadIdx.x;
    if (t < NBK) h[t] = 0;
    __syncthreads();
    int base = blockIdx.x * EPB;
#pragma unroll
    for (int it = 0; it < EPB / 256; ++it) {
        int e = base + it * 256 + t;
        if (e < N_EDGES) atomicAdd(&h[ei[N_EDGES + e] >> 8], 1);
    }
    __syncthreads();
    if (t < NBK) blkcnt[t * NBLK + blockIdx.x] = h[t];   // transposed
}

// ---------------- pass 2a: within-bucket scan over blocks ----------------

__global__ __launch_bounds__(128) void k_scanA(const int* __restrict__ blkcnt,
                                               int* __restrict__ boff,
                                               int* __restrict__ btot) {
    __shared__ int s[128];
    int b = blockIdx.x, t = threadIdx.x;
    int v = (t < NBLK) ? blkcnt[b * NBLK + t] : 0;
    s[t] = v;
    __syncthreads();
#pragma unroll
    for (int off = 1; off < 128; off <<= 1) {
        int u = (t >= off) ? s[t - off] : 0;
        __syncthreads();
        s[t] += u;
        __syncthreads();
    }
    if (t < NBLK) boff[b * NBLK + t] = s[t] - v;   // exclusive
    if (t == 127) btot[b] = s[127];
}

// ---------------- pass 2b: scan bucket totals -> bucket bases ----------------

__global__ __launch_bounds__(256) void k_scanB(const int* __restrict__ btot,
                                               int* __restrict__ bbase,
                                               float* __restrict__ st) {
    __shared__ int s[256];
    int t = threadIdx.x;
    int v = (t < NBK) ? btot[t] : 0;
    s[t] = v;
    __syncthreads();
#pragma unroll
    for (int off = 1; off < 256; off <<= 1) {
        int u = (t >= off) ? s[t - off] : 0;
        __syncthreads();
        s[t] += u;
        __syncthreads();
    }
    if (t < NBK) bbase[t] = s[t] - v;
    if (t == 0)  bbase[NBK] = N_EDGES;
    if (t < 2 * HID_F) st[t] = 0.f;   // zero BN stats here
}

// ---------------- pass 3: bucket-sort edges block-locally, coalesced out ----

__global__ __launch_bounds__(256) void k_binscatter(const int* __restrict__ ei,
                                                    const int* __restrict__ boff,
                                                    const int* __restrict__ bbase,
                                                    unsigned int* __restrict__ bket) {
    __shared__ int h[NBK], off[NBK], fill[NBK];
    __shared__ int s[256];
    __shared__ unsigned int staged[EPB];   // 32 KB
    int t = threadIdx.x;
    if (t < NBK) h[t] = 0;
    __syncthreads();
    int base = blockIdx.x * EPB;
    int nedge = N_EDGES - base; if (nedge > EPB) nedge = EPB;
#pragma unroll
    for (int it = 0; it < EPB / 256; ++it) {
        int e = base + it * 256 + t;
        if (e < N_EDGES) atomicAdd(&h[ei[N_EDGES + e] >> 8], 1);
    }
    __syncthreads();
    int v = (t < NBK) ? h[t] : 0;
    s[t] = v;
    __syncthreads();
#pragma unroll
    for (int o = 1; o < 256; o <<= 1) {
        int u = (t >= o) ? s[t - o] : 0;
        __syncthreads();
        s[t] += u;
        __syncthreads();
    }
    if (t < NBK) { off[t] = s[t] - v; fill[t] = s[t] - v; }
    __syncthreads();
#pragma unroll
    for (int it = 0; it < EPB / 256; ++it) {
        int e = base + it * 256 + t;
        if (e < N_EDGES) {
            int srcv = ei[e], dstv = ei[N_EDGES + e];
            int p = atomicAdd(&fill[dstv >> 8], 1);
            staged[p] = ((unsigned int)dstv << 16) | (unsigned int)srcv;
        }
    }
    __syncthreads();
    // coalesced copy-out: contiguous local i maps to contiguous global runs
    for (int i = t; i < nedge; i += 256) {
        unsigned int k = staged[i];
        int bk = k >> 24;                 // dst >> 8
        int rank = i - off[bk];
        bket[bbase[bk] + boff[bk * NBLK + blockIdx.x] + rank] = k;
    }
}

// ---------------- pass 4: per-bucket counting sort in LDS ----------------
// emits rowptr, dinv, and dst-sorted src ids (ssrc) with coalesced writes

__global__ __launch_bounds__(256) void k_bucket(const unsigned int* __restrict__ bket,
                                                const int* __restrict__ bbase,
                                                int* __restrict__ rowptr,
                                                float* __restrict__ dinv,
                                                unsigned short* __restrict__ ssrc) {
    __shared__ unsigned int keys[CAP];     // 24 KB
    __shared__ unsigned short outb[CAP];   // 12 KB
    __shared__ int cnt[256], loc[256], fill[256], s[256];
    int b = blockIdx.x, t = threadIdx.x;
    int base = bbase[b];
    int end  = bbase[b + 1];
    int size = end - base;
    bool small = (size <= CAP);
    cnt[t] = 0;
    __syncthreads();
    if (small) {
        for (int i = t; i < size; i += 256) {
            unsigned int k = bket[base + i];
            keys[i] = k;
            atomicAdd(&cnt[(k >> 16) & 255], 1);
        }
    } else {
        for (int i = t; i < size; i += 256)
            atomicAdd(&cnt[(bket[base + i] >> 16) & 255], 1);
    }
    __syncthreads();
    int v = cnt[t];
    s[t] = v;
    __syncthreads();
#pragma unroll
    for (int o = 1; o < 256; o <<= 1) {
        int u = (t >= o) ? s[t - o] : 0;
        __syncthreads();
        s[t] += u;
        __syncthreads();
    }
    loc[t]  = s[t] - v;
    fill[t] = s[t] - v;
    int node = b * 256 + t;
    if (node < N_NODES) {
        rowptr[node] = base + loc[t];
        dinv[node]   = rsqrtf((float)v + 1.0f);   // + self-loop
    }
    if (b == 0 && t == 0) rowptr[N_NODES] = N_EDGES;
    __syncthreads();
    if (small) {
        for (int i = t; i < size; i += 256) {
            unsigned int k = keys[i];
            int p = atomicAdd(&fill[(k >> 16) & 255], 1);
            outb[p] = (unsigned short)(k & 0xFFFFu);
        }
        __syncthreads();
        for (int i = t; i < size; i += 256) ssrc[base + i] = outb[i];
    } else {   // fallback (never taken for this input): direct global scatter
        for (int i = t; i < size; i += 256) {
            unsigned int k = bket[base + i];
            int p = atomicAdd(&fill[(k >> 16) & 255], 1);
            ssrc[base + p] = (unsigned short)(k & 0xFFFFu);
        }
    }
}

// ---------------- GEMM1: h1s[N,64] = (x @ W1) * dinv, fp16 out ----------------

__global__ __launch_bounds__(256) void k_gemm1(const float* __restrict__ x,
                                               const float* __restrict__ W1,
                                               const float* __restrict__ dinv,
                                               __half* __restrict__ h1s) {
    __shared__ float sW[IN_F][HID_F];    // 32768 B
    __shared__ float sX[32][IN_F + 1];   // 16512 B
    int t = threadIdx.x;
    for (int i = t; i < IN_F * HID_F; i += 256)
        sW[i >> 6][i & 63] = W1[i];
    int row0 = blockIdx.x * 32;
    for (int i = t; i < 32 * 32; i += 256) {
        int r  = i >> 5;
        int c4 = i & 31;
        int gr = row0 + r;
        float4 v = make_float4(0.f, 0.f, 0.f, 0.f);
        if (gr < N_NODES) v = ((const float4*)x)[gr * 32 + c4];
        sX[r][c4 * 4 + 0] = v.x;
        sX[r][c4 * 4 + 1] = v.y;
        sX[r][c4 * 4 + 2] = v.z;
        sX[r][c4 * 4 + 3] = v.w;
    }
    __syncthreads();
    int c  = t & 63;
    int rg = t >> 6;
    float acc[8];
#pragma unroll
    for (int j = 0; j < 8; ++j) acc[j] = 0.f;
#pragma unroll 4
    for (int k = 0; k < IN_F; ++k) {
        float w = sW[k][c];
#pragma unroll
        for (int j = 0; j < 8; ++j)
            acc[j] += sX[rg * 8 + j][k] * w;
    }
#pragma unroll
    for (int j = 0; j < 8; ++j) {
        int gr = row0 + rg * 8 + j;
        if (gr < N_NODES) h1s[gr * HID_F + c] = __float2half(acc[j] * dinv[gr]);
    }
}

// ---------------- layer-1 aggregation: fp16 gather -> fp16 out ----------------

__global__ __launch_bounds__(256) void k_agg1(const int* __restrict__ rowptr,
                                              const unsigned short* __restrict__ ssrc,
                                              const float* __restrict__ dinv,
                                              const __half* __restrict__ h1s,
                                              const float* __restrict__ b1,
                                              __half* __restrict__ agg1h) {
    int lane = threadIdx.x & 63;
    int d = blockIdx.x * 4 + (threadIdx.x >> 6);
    if (d >= N_NODES) return;
    int base = rowptr[d];
    int end  = rowptr[d + 1];
    float acc = __half2float(h1s[d * HID_F + lane]);   // self-loop (pre-scaled)
    for (int j0 = base; j0 < end; j0 += 64) {
        int idx = j0 + lane;
        int sl = (idx < end) ? (int)ssrc[idx] : 0;
        int m = end - j0; if (m > 64) m = 64;
#pragma unroll 4
        for (int j = 0; j < m; ++j) {
            int s = __shfl(sl, j);
            acc += __half2float(h1s[s * HID_F + lane]);
        }
    }
    agg1h[d * HID_F + lane] = __float2half(acc * dinv[d] + b1[lane]);
}

// ---------------- BN statistics (fp16 in, fp32 accumulate) ----------------

__global__ __launch_bounds__(256) void k_bn_reduce(const __half* __restrict__ agg1h,
                                                   float* __restrict__ st) {
    int c    = threadIdx.x & 63;
    int rloc = threadIdx.x >> 6;
    float s = 0.f, s2 = 0.f;
    for (int r = blockIdx.x * 4 + rloc; r < N_NODES; r += gridDim.x * 4) {
        float v = __half2float(agg1h[r * HID_F + c]);
        s  += v;
        s2 += v * v;
    }
    __shared__ float ls[4][HID_F], ls2[4][HID_F];
    ls[rloc][c]  = s;
    ls2[rloc][c] = s2;
    __syncthreads();
    if (rloc == 0) {
        s  = ls[0][c] + ls[1][c] + ls[2][c] + ls[3][c];
        s2 = ls2[0][c] + ls2[1][c] + ls2[2][c] + ls2[3][c];
        atomicAdd(&st[c], s);
        atomicAdd(&st[HID_F + c], s2);
    }
}

// ---------------- GEMM2 fused BN + ReLU, epilogue *dinv, fp16 in/out --------

__global__ __launch_bounds__(256) void k_gemm2(const __half* __restrict__ agg1h,
                                               const float* __restrict__ st,
                                               const float* __restrict__ gamma,
                                               const float* __restrict__ beta,
                                               const float* __restrict__ W2,
                                               const float* __restrict__ dinv,
                                               __half* __restrict__ h2s) {
    __shared__ float sW[HID_F][OUT_F];
    __shared__ float sScale[HID_F], sShift[HID_F];
    int t = threadIdx.x;
    for (int i = t; i < HID_F * OUT_F; i += 256)
        sW[i / OUT_F][i % OUT_F] = W2[i];
    if (t < HID_F) {
        float mean = st[t] * (1.0f / N_NODES);
        float var  = st[HID_F + t] * (1.0f / N_NODES) - mean * mean;
        float inv  = rsqrtf(var + 1e-5f);
        float g    = gamma[t];
        sScale[t]  = g * inv;
        sShift[t]  = beta[t] - g * inv * mean;
    }
    __syncthreads();
    int row = blockIdx.x * 256 + t;
    if (row >= N_NODES) return;
    float acc[OUT_F];
#pragma unroll
    for (int c = 0; c < OUT_F; ++c) acc[c] = 0.f;
    const __half* arow = agg1h + (size_t)row * HID_F;
#pragma unroll 4
    for (int k = 0; k < HID_F; ++k) {
        float v = fmaxf(__half2float(arow[k]) * sScale[k] + sShift[k], 0.f);
#pragma unroll
        for (int c = 0; c < OUT_F; ++c) acc[c] += v * sW[k][c];
    }
    float di = dinv[row];
    __half* orow = h2s + (size_t)row * OUT_F;
#pragma unroll
    for (int c = 0; c < OUT_F; ++c) orow[c] = __float2half(acc[c] * di);
}

// ---------------- layer-2 aggregation: fp16 gather into d_out ----------------

__global__ __launch_bounds__(256) void k_agg2(const int* __restrict__ rowptr,
                                              const unsigned short* __restrict__ ssrc,
                                              const float* __restrict__ dinv,
                                              const __half* __restrict__ h2s,
                                              const float* __restrict__ b2,
                                              float* __restrict__ out) {
    int lane = threadIdx.x & 63;
    int d = blockIdx.x * 4 + (threadIdx.x >> 6);
    if (d >= N_NODES) return;
    int base = rowptr[d];
    int end  = rowptr[d + 1];
    int cl = (lane < OUT_F) ? lane : 0;
    float acc = __half2float(h2s[d * OUT_F + cl]);
    for (int j0 = base; j0 < end; j0 += 64) {
        int idx = j0 + lane;
        int sl = (idx < end) ? (int)ssrc[idx] : 0;
        int m = end - j0; if (m > 64) m = 64;
#pragma unroll 4
        for (int j = 0; j < m; ++j) {
            int s = __shfl(sl, j);
            acc += __half2float(h2s[s * OUT_F + cl]);
        }
    }
    if (lane < OUT_F)
        out[d * OUT_F + lane] = acc * dinv[d] + b2[lane];
}

// ---------------- launch ----------------

extern "C" void kernel_launch(void* const* d_in, const int* in_sizes, int n_in,
                              void* d_out, int out_size, void* d_ws, size_t ws_size,
                              hipStream_t stream) {
    const float* x     = (const float*)d_in[0];
    const int*   ei    = (const int*)d_in[1];
    const float* W1    = (const float*)d_in[2];
    const float* b1    = (const float*)d_in[3];
    const float* gamma = (const float*)d_in[4];
    const float* beta  = (const float*)d_in[5];
    const float* W2    = (const float*)d_in[6];
    const float* b2    = (const float*)d_in[7];
    float* out = (float*)d_out;

    char* ws = (char*)d_ws;
    int*            blkcnt = (int*)           (ws + 0);          //  76,832 B
    int*            boff   = (int*)           (ws + 77824);      //  76,832 B
    int*            btot   = (int*)           (ws + 155648);     //     784 B
    int*            bbase  = (int*)           (ws + 156672);     //     788 B
    int*            rowptr = (int*)           (ws + 157696);     // 200,004 B
    float*          dinv   = (float*)         (ws + 358400);     // 200,000 B
    float*          st     = (float*)         (ws + 559104);     //     512 B
    unsigned int*   bket   = (unsigned int*)  (ws + 560128);     // 3,200,000 B
    unsigned short* ssrc   = (unsigned short*)(ws + 3760128);    // 1,600,000 B
    __half*         h1s    = (__half*)        (ws + 5360128);    // 6,400,000 B
    __half*         agg1h  = (__half*)        (ws + 11760128);   // 6,400,000 B
    __half*         h2s    = (__half*)        (ws + 18160128);   // 4,000,000 B
    // total ~22.2 MB

    k_hist<<<NBLK, 256, 0, stream>>>(ei, blkcnt);
    k_scanA<<<NBK, 128, 0, stream>>>(blkcnt, boff, btot);
    k_scanB<<<1, 256, 0, stream>>>(btot, bbase, st);
    k_binscatter<<<NBLK, 256, 0, stream>>>(ei, boff, bbase, bket);
    k_bucket<<<NBK, 256, 0, stream>>>(bket, bbase, rowptr, dinv, ssrc);

    k_gemm1<<<NB_G1, 256, 0, stream>>>(x, W1, dinv, h1s);
    k_agg1<<<(N_NODES + 3) / 4, 256, 0, stream>>>(rowptr, ssrc, dinv, h1s, b1, agg1h);

    k_bn_reduce<<<512, 256, 0, stream>>>(agg1h, st);
    k_gemm2<<<(N_NODES + 255) / 256, 256, 0, stream>>>(agg1h, st, gamma, beta, W2, dinv, h2s);
    k_agg2<<<(N_NODES + 3) / 4, 256, 0, stream>>>(rowptr, ssrc, dinv, h2s, b2, out);
}

// Round 6
// 243.518 us; speedup vs baseline: 2.3220x; 1.1864x over previous
//
#include <hip/hip_runtime.h>
#include <hip/hip_fp16.h>

#define N_NODES 50000
#define N_EDGES 800000
#define IN_F    128
#define HID_F   64
#define OUT_F   40

#define EPB   8192                       // edges per sort block
#define NBLK  ((N_EDGES + EPB - 1) / EPB)   // 98
#define NBK   ((N_NODES + 255) / 256)       // 196 buckets (dst >> 8)
#define CAP   6144                       // per-bucket LDS capacity (avg 4096, sd 64)
#define NB_G1 ((N_NODES + 31) / 32)      // 1563 gemm1 blocks

// ---------------- pass 1: per-block bucket histogram ----------------

__global__ __launch_bounds__(256) void k_hist(const int* __restrict__ ei,
                                              int* __restrict__ blkcnt) {
    __shared__ int h[NBK];
    int t = threadIdx.x;
    if (t < NBK) h[t] = 0;
    __syncthreads();
    int base = blockIdx.x * EPB;
#pragma unroll
    for (int it = 0; it < EPB / 256; ++it) {
        int e = base + it * 256 + t;
        if (e < N_EDGES) atomicAdd(&h[ei[N_EDGES + e] >> 8], 1);
    }
    __syncthreads();
    if (t < NBK) blkcnt[t * NBLK + blockIdx.x] = h[t];   // transposed
}

// ---------------- pass 2a: within-bucket scan over blocks ----------------

__global__ __launch_bounds__(128) void k_scanA(const int* __restrict__ blkcnt,
                                               int* __restrict__ boff,
                                               int* __restrict__ btot) {
    __shared__ int s[128];
    int b = blockIdx.x, t = threadIdx.x;
    int v = (t < NBLK) ? blkcnt[b * NBLK + t] : 0;
    s[t] = v;
    __syncthreads();
#pragma unroll
    for (int off = 1; off < 128; off <<= 1) {
        int u = (t >= off) ? s[t - off] : 0;
        __syncthreads();
        s[t] += u;
        __syncthreads();
    }
    if (t < NBLK) boff[b * NBLK + t] = s[t] - v;   // exclusive
    if (t == 127) btot[b] = s[127];
}

// ---------------- pass 2b: scan bucket totals -> bucket bases ----------------

__global__ __launch_bounds__(256) void k_scanB(const int* __restrict__ btot,
                                               int* __restrict__ bbase,
                                               float* __restrict__ st) {
    __shared__ int s[256];
    int t = threadIdx.x;
    int v = (t < NBK) ? btot[t] : 0;
    s[t] = v;
    __syncthreads();
#pragma unroll
    for (int off = 1; off < 256; off <<= 1) {
        int u = (t >= off) ? s[t - off] : 0;
        __syncthreads();
        s[t] += u;
        __syncthreads();
    }
    if (t < NBK) bbase[t] = s[t] - v;
    if (t == 0)  bbase[NBK] = N_EDGES;
    if (t < 2 * HID_F) st[t] = 0.f;   // zero BN stats here
}

// ---------------- pass 3: bucket-sort edges block-locally, coalesced out ----

__global__ __launch_bounds__(256) void k_binscatter(const int* __restrict__ ei,
                                                    const int* __restrict__ boff,
                                                    const int* __restrict__ bbase,
                                                    unsigned int* __restrict__ bket) {
    __shared__ int h[NBK], off[NBK], fill[NBK];
    __shared__ int s[256];
    __shared__ unsigned int staged[EPB];   // 32 KB
    int t = threadIdx.x;
    if (t < NBK) h[t] = 0;
    __syncthreads();
    int base = blockIdx.x * EPB;
    int nedge = N_EDGES - base; if (nedge > EPB) nedge = EPB;
#pragma unroll
    for (int it = 0; it < EPB / 256; ++it) {
        int e = base + it * 256 + t;
        if (e < N_EDGES) atomicAdd(&h[ei[N_EDGES + e] >> 8], 1);
    }
    __syncthreads();
    int v = (t < NBK) ? h[t] : 0;
    s[t] = v;
    __syncthreads();
#pragma unroll
    for (int o = 1; o < 256; o <<= 1) {
        int u = (t >= o) ? s[t - o] : 0;
        __syncthreads();
        s[t] += u;
        __syncthreads();
    }
    if (t < NBK) { off[t] = s[t] - v; fill[t] = s[t] - v; }
    __syncthreads();
#pragma unroll
    for (int it = 0; it < EPB / 256; ++it) {
        int e = base + it * 256 + t;
        if (e < N_EDGES) {
            int srcv = ei[e], dstv = ei[N_EDGES + e];
            int p = atomicAdd(&fill[dstv >> 8], 1);
            staged[p] = ((unsigned int)dstv << 16) | (unsigned int)srcv;
        }
    }
    __syncthreads();
    // coalesced copy-out: contiguous local i maps to contiguous global runs
    for (int i = t; i < nedge; i += 256) {
        unsigned int k = staged[i];
        int bk = k >> 24;                 // dst >> 8
        int rank = i - off[bk];
        bket[bbase[bk] + boff[bk * NBLK + blockIdx.x] + rank] = k;
    }
}

// ---------------- pass 4: per-bucket counting sort in LDS ----------------

__global__ __launch_bounds__(256) void k_bucket(const unsigned int* __restrict__ bket,
                                                const int* __restrict__ bbase,
                                                int* __restrict__ rowptr,
                                                float* __restrict__ dinv,
                                                unsigned short* __restrict__ ssrc) {
    __shared__ unsigned int keys[CAP];     // 24 KB
    __shared__ unsigned short outb[CAP];   // 12 KB
    __shared__ int cnt[256], loc[256], fill[256], s[256];
    int b = blockIdx.x, t = threadIdx.x;
    int base = bbase[b];
    int end  = bbase[b + 1];
    int size = end - base;
    bool small = (size <= CAP);
    cnt[t] = 0;
    __syncthreads();
    if (small) {
        for (int i = t; i < size; i += 256) {
            unsigned int k = bket[base + i];
            keys[i] = k;
            atomicAdd(&cnt[(k >> 16) & 255], 1);
        }
    } else {
        for (int i = t; i < size; i += 256)
            atomicAdd(&cnt[(bket[base + i] >> 16) & 255], 1);
    }
    __syncthreads();
    int v = cnt[t];
    s[t] = v;
    __syncthreads();
#pragma unroll
    for (int o = 1; o < 256; o <<= 1) {
        int u = (t >= o) ? s[t - o] : 0;
        __syncthreads();
        s[t] += u;
        __syncthreads();
    }
    loc[t]  = s[t] - v;
    fill[t] = s[t] - v;
    int node = b * 256 + t;
    if (node < N_NODES) {
        rowptr[node] = base + loc[t];
        dinv[node]   = rsqrtf((float)v + 1.0f);   // + self-loop
    }
    if (b == 0 && t == 0) rowptr[N_NODES] = N_EDGES;
    __syncthreads();
    if (small) {
        for (int i = t; i < size; i += 256) {
            unsigned int k = keys[i];
            int p = atomicAdd(&fill[(k >> 16) & 255], 1);
            outb[p] = (unsigned short)(k & 0xFFFFu);
        }
        __syncthreads();
        for (int i = t; i < size; i += 256) ssrc[base + i] = outb[i];
    } else {   // fallback (never taken for this input)
        for (int i = t; i < size; i += 256) {
            unsigned int k = bket[base + i];
            int p = atomicAdd(&fill[(k >> 16) & 255], 1);
            ssrc[base + p] = (unsigned short)(k & 0xFFFFu);
        }
    }
}

// ---------------- GEMM1: h1s[N,64] = (x @ W1) * dinv, fp16 out ----------------

__global__ __launch_bounds__(256) void k_gemm1(const float* __restrict__ x,
                                               const float* __restrict__ W1,
                                               const float* __restrict__ dinv,
                                               __half* __restrict__ h1s) {
    __shared__ float sW[IN_F][HID_F];    // 32768 B
    __shared__ float sX[32][IN_F + 1];   // 16512 B
    int t = threadIdx.x;
    for (int i = t; i < IN_F * HID_F; i += 256)
        sW[i >> 6][i & 63] = W1[i];
    int row0 = blockIdx.x * 32;
    for (int i = t; i < 32 * 32; i += 256) {
        int r  = i >> 5;
        int c4 = i & 31;
        int gr = row0 + r;
        float4 v = make_float4(0.f, 0.f, 0.f, 0.f);
        if (gr < N_NODES) v = ((const float4*)x)[gr * 32 + c4];
        sX[r][c4 * 4 + 0] = v.x;
        sX[r][c4 * 4 + 1] = v.y;
        sX[r][c4 * 4 + 2] = v.z;
        sX[r][c4 * 4 + 3] = v.w;
    }
    __syncthreads();
    int c  = t & 63;
    int rg = t >> 6;
    float acc[8];
#pragma unroll
    for (int j = 0; j < 8; ++j) acc[j] = 0.f;
#pragma unroll 4
    for (int k = 0; k < IN_F; ++k) {
        float w = sW[k][c];
#pragma unroll
        for (int j = 0; j < 8; ++j)
            acc[j] += sX[rg * 8 + j][k] * w;
    }
#pragma unroll
    for (int j = 0; j < 8; ++j) {
        int gr = row0 + rg * 8 + j;
        if (gr < N_NODES) h1s[gr * HID_F + c] = __float2half(acc[j] * dinv[gr]);
    }
}

// ---------------- layer-1 aggregation: deep-MLP fp16 gather ----------------
// 16 independent loads in flight per wave (clamped index + masked accumulate)

__global__ __launch_bounds__(256) void k_agg1(const int* __restrict__ rowptr,
                                              const unsigned short* __restrict__ ssrc,
                                              const float* __restrict__ dinv,
                                              const __half* __restrict__ h1s,
                                              const float* __restrict__ b1,
                                              __half* __restrict__ agg1h) {
    int lane = threadIdx.x & 63;
    int d = blockIdx.x * 4 + (threadIdx.x >> 6);
    if (d >= N_NODES) return;
    int base = rowptr[d];
    int end  = rowptr[d + 1];
    float acc = __half2float(h1s[d * HID_F + lane]);   // self-loop (pre-scaled)
    for (int j0 = base; j0 < end; j0 += 64) {
        int idx = j0 + lane;
        int sl = (idx < end) ? (int)ssrc[idx] : 0;
        int m = end - j0; if (m > 64) m = 64;
        for (int c0 = 0; c0 < m; c0 += 16) {
            float v[16];
#pragma unroll
            for (int k = 0; k < 16; ++k) {
                int j  = c0 + k;
                int jj = (j < m) ? j : (m - 1);      // wave-uniform clamp
                int s  = __shfl(sl, jj);
                v[k] = __half2float(h1s[s * HID_F + lane]);
            }
#pragma unroll
            for (int k = 0; k < 16; ++k)
                acc += (c0 + k < m) ? v[k] : 0.f;
        }
    }
    agg1h[d * HID_F + lane] = __float2half(acc * dinv[d] + b1[lane]);
}

// ---------------- BN statistics (fp16 in, fp32 accumulate) ----------------

__global__ __launch_bounds__(256) void k_bn_reduce(const __half* __restrict__ agg1h,
                                                   float* __restrict__ st) {
    int c    = threadIdx.x & 63;
    int rloc = threadIdx.x >> 6;
    float s = 0.f, s2 = 0.f;
    for (int r = blockIdx.x * 4 + rloc; r < N_NODES; r += gridDim.x * 4) {
        float v = __half2float(agg1h[r * HID_F + c]);
        s  += v;
        s2 += v * v;
    }
    __shared__ float ls[4][HID_F], ls2[4][HID_F];
    ls[rloc][c]  = s;
    ls2[rloc][c] = s2;
    __syncthreads();
    if (rloc == 0) {
        s  = ls[0][c] + ls[1][c] + ls[2][c] + ls[3][c];
        s2 = ls2[0][c] + ls2[1][c] + ls2[2][c] + ls2[3][c];
        atomicAdd(&st[c], s);
        atomicAdd(&st[HID_F + c], s2);
    }
}

// ---------------- GEMM2 fused BN + ReLU, epilogue *dinv, fp16 in/out --------

__global__ __launch_bounds__(256) void k_gemm2(const __half* __restrict__ agg1h,
                                               const float* __restrict__ st,
                                               const float* __restrict__ gamma,
                                               const float* __restrict__ beta,
                                               const float* __restrict__ W2,
                                               const float* __restrict__ dinv,
                                               __half* __restrict__ h2s) {
    __shared__ float sW[HID_F][OUT_F];
    __shared__ float sScale[HID_F], sShift[HID_F];
    int t = threadIdx.x;
    for (int i = t; i < HID_F * OUT_F; i += 256)
        sW[i / OUT_F][i % OUT_F] = W2[i];
    if (t < HID_F) {
        float mean = st[t] * (1.0f / N_NODES);
        float var  = st[HID_F + t] * (1.0f / N_NODES) - mean * mean;
        float inv  = rsqrtf(var + 1e-5f);
        float g    = gamma[t];
        sScale[t]  = g * inv;
        sShift[t]  = beta[t] - g * inv * mean;
    }
    __syncthreads();
    int row = blockIdx.x * 256 + t;
    if (row >= N_NODES) return;
    float acc[OUT_F];
#pragma unroll
    for (int c = 0; c < OUT_F; ++c) acc[c] = 0.f;
    const __half* arow = agg1h + (size_t)row * HID_F;
#pragma unroll 4
    for (int k = 0; k < HID_F; ++k) {
        float v = fmaxf(__half2float(arow[k]) * sScale[k] + sShift[k], 0.f);
#pragma unroll
        for (int c = 0; c < OUT_F; ++c) acc[c] += v * sW[k][c];
    }
    float di = dinv[row];
    __half* orow = h2s + (size_t)row * OUT_F;
#pragma unroll
    for (int c = 0; c < OUT_F; ++c) orow[c] = __float2half(acc[c] * di);
}

// ---------------- layer-2 aggregation: deep-MLP fp16 gather -> d_out --------

__global__ __launch_bounds__(256) void k_agg2(const int* __restrict__ rowptr,
                                              const unsigned short* __restrict__ ssrc,
                                              const float* __restrict__ dinv,
                                              const __half* __restrict__ h2s,
                                              const float* __restrict__ b2,
                                              float* __restrict__ out) {
    int lane = threadIdx.x & 63;
    int d = blockIdx.x * 4 + (threadIdx.x >> 6);
    if (d >= N_NODES) return;
    int base = rowptr[d];
    int end  = rowptr[d + 1];
    int cl = (lane < OUT_F) ? lane : 0;
    float acc = __half2float(h2s[d * OUT_F + cl]);
    for (int j0 = base; j0 < end; j0 += 64) {
        int idx = j0 + lane;
        int sl = (idx < end) ? (int)ssrc[idx] : 0;
        int m = end - j0; if (m > 64) m = 64;
        for (int c0 = 0; c0 < m; c0 += 16) {
            float v[16];
#pragma unroll
            for (int k = 0; k < 16; ++k) {
                int j  = c0 + k;
                int jj = (j < m) ? j : (m - 1);
                int s  = __shfl(sl, jj);
                v[k] = __half2float(h2s[s * OUT_F + cl]);
            }
#pragma unroll
            for (int k = 0; k < 16; ++k)
                acc += (c0 + k < m) ? v[k] : 0.f;
        }
    }
    if (lane < OUT_F)
        out[d * OUT_F + lane] = acc * dinv[d] + b2[lane];
}

// ---------------- launch ----------------

extern "C" void kernel_launch(void* const* d_in, const int* in_sizes, int n_in,
                              void* d_out, int out_size, void* d_ws, size_t ws_size,
                              hipStream_t stream) {
    const float* x     = (const float*)d_in[0];
    const int*   ei    = (const int*)d_in[1];
    const float* W1    = (const float*)d_in[2];
    const float* b1    = (const float*)d_in[3];
    const float* gamma = (const float*)d_in[4];
    const float* beta  = (const float*)d_in[5];
    const float* W2    = (const float*)d_in[6];
    const float* b2    = (const float*)d_in[7];
    float* out = (float*)d_out;

    char* ws = (char*)d_ws;
    int*            blkcnt = (int*)           (ws + 0);          //  76,832 B
    int*            boff   = (int*)           (ws + 77824);      //  76,832 B
    int*            btot   = (int*)           (ws + 155648);     //     784 B
    int*            bbase  = (int*)           (ws + 156672);     //     788 B
    int*            rowptr = (int*)           (ws + 157696);     // 200,004 B
    float*          dinv   = (float*)         (ws + 358400);     // 200,000 B
    float*          st     = (float*)         (ws + 559104);     //     512 B
    unsigned int*   bket   = (unsigned int*)  (ws + 560128);     // 3,200,000 B
    unsigned short* ssrc   = (unsigned short*)(ws + 3760128);    // 1,600,000 B
    __half*         h1s    = (__half*)        (ws + 5360128);    // 6,400,000 B
    __half*         agg1h  = (__half*)        (ws + 11760128);   // 6,400,000 B
    __half*         h2s    = (__half*)        (ws + 18160128);   // 4,000,000 B
    // total ~22.2 MB

    k_hist<<<NBLK, 256, 0, stream>>>(ei, blkcnt);
    k_scanA<<<NBK, 128, 0, stream>>>(blkcnt, boff, btot);
    k_scanB<<<1, 256, 0, stream>>>(btot, bbase, st);
    k_binscatter<<<NBLK, 256, 0, stream>>>(ei, boff, bbase, bket);
    k_bucket<<<NBK, 256, 0, stream>>>(bket, bbase, rowptr, dinv, ssrc);

    k_gemm1<<<NB_G1, 256, 0, stream>>>(x, W1, dinv, h1s);
    k_agg1<<<(N_NODES + 3) / 4, 256, 0, stream>>>(rowptr, ssrc, dinv, h1s, b1, agg1h);

    k_bn_reduce<<<512, 256, 0, stream>>>(agg1h, st);
    k_gemm2<<<(N_NODES + 255) / 256, 256, 0, stream>>>(agg1h, st, gamma, beta, W2, dinv, h2s);
    k_agg2<<<(N_NODES + 3) / 4, 256, 0, stream>>>(rowptr, ssrc, dinv, h2s, b2, out);
}

// Round 7
// 232.632 us; speedup vs baseline: 2.4307x; 1.0468x over previous
//
#include <hip/hip_runtime.h>
#include <hip/hip_fp16.h>

#define N_NODES 50000
#define N_EDGES 800000
#define IN_F    128
#define HID_F   64
#define OUT_F   40

#define EPB   4096                          // edges per sort block
#define NBLK  ((N_EDGES + EPB - 1) / EPB)   // 196 sort blocks
#define NBK   ((N_NODES + 255) / 256)       // 196 buckets (dst >> 8)
#define CAP   6144                          // per-bucket LDS cap (avg 4082, sd 64)
#define NREP  32                            // BN-stat atomic replicas
#define NB_G1 ((N_NODES + 31) / 32)         // 1563 gemm1 blocks

// ============ pass 1: per-block bucket sort, block-local output ============
// Each block sorts its 4096 edges by bucket (dst>>8) in LDS, writes the
// sorted run to its OWN contiguous region of bket (fully coalesced), plus
// its per-bucket counts to blkcnt[bucket][block]. No global scan needed yet.

__global__ __launch_bounds__(512) void k_binscatter(const int* __restrict__ ei,
                                                    int* __restrict__ blkcnt,
                                                    unsigned int* __restrict__ bket,
                                                    float* __restrict__ st2) {
    __shared__ int h[256], fill[256], sc[256];
    __shared__ unsigned int staged[EPB];   // 16 KB
    int t = threadIdx.x;
    if (t < 256) h[t] = 0;
    if (blockIdx.x == 0)                   // zero BN-stat replicas once
        for (int i = t; i < NREP * 2 * HID_F; i += 512) st2[i] = 0.f;
    __syncthreads();
    int base = blockIdx.x * EPB;
    int nedge = N_EDGES - base; if (nedge > EPB) nedge = EPB;
#pragma unroll
    for (int it = 0; it < EPB / 512; ++it) {
        int e = base + it * 512 + t;
        if (e < N_EDGES) atomicAdd(&h[ei[N_EDGES + e] >> 8], 1);
    }
    __syncthreads();
    int v = (t < 256) ? h[t] : 0;
    if (t < 256) sc[t] = v;
    __syncthreads();
#pragma unroll
    for (int o = 1; o < 256; o <<= 1) {
        int u = (t < 256 && t >= o) ? sc[t - o] : 0;
        __syncthreads();
        if (t < 256) sc[t] += u;
        __syncthreads();
    }
    if (t < 256) fill[t] = sc[t] - v;      // exclusive
    __syncthreads();
#pragma unroll
    for (int it = 0; it < EPB / 512; ++it) {
        int e = base + it * 512 + t;
        if (e < N_EDGES) {
            int srcv = ei[e], dstv = ei[N_EDGES + e];
            int p = atomicAdd(&fill[dstv >> 8], 1);
            staged[p] = ((unsigned int)dstv << 16) | (unsigned int)srcv;
        }
    }
    __syncthreads();
    for (int i = t; i < nedge; i += 512) bket[base + i] = staged[i];   // coalesced
    if (t < NBK) blkcnt[t * NBLK + blockIdx.x] = h[t];
}

// ============ pass 2: per-bucket CSR build (scans done in-kernel) ============
// Block b: computes its global CSR base + per-source-block offsets from
// blkcnt (L2-hot), gathers its ~4096 keys from 196 segments into LDS,
// counting-sorts by dst, emits rowptr / dinv / coalesced ssrc.

__global__ __launch_bounds__(512) void k_bucket(const int* __restrict__ blkcnt,
                                                const unsigned int* __restrict__ bket,
                                                int* __restrict__ rowptr,
                                                float* __restrict__ dinv,
                                                unsigned short* __restrict__ ssrc) {
    __shared__ unsigned int keys[CAP];     // 24 KB
    __shared__ unsigned short outb[CAP];   // 12 KB
    __shared__ int colpre[256], rowcnt[256], boffs[256];
    __shared__ int cnt[256], loc[256], fillb[256], sc[256];
    __shared__ int wsum[8], sbase, ssize;
    int b = blockIdx.x, t = threadIdx.x;
    int lane = t & 63, wid = t >> 6;

    // --- preamble: column prefixes (this bucket's segment starts) + row ---
    int cp = 0, rc = 0;
    if (t < NBLK) {
        for (int bp = 0; bp < b; ++bp) cp += blkcnt[bp * NBLK + t];   // coalesced
        rc = blkcnt[b * NBLK + t];
    }
    if (t < 256) { colpre[t] = cp; rowcnt[t] = rc; }
    // bbase = sum of cp over all columns (edges of buckets < b)
    int red = cp;
#pragma unroll
    for (int o = 32; o > 0; o >>= 1) red += __shfl_down(red, o);
    if (lane == 0) wsum[wid] = red;
    __syncthreads();
    if (t == 0) {
        int s = 0;
#pragma unroll
        for (int r = 0; r < 8; ++r) s += wsum[r];
        sbase = s;
    }
    // boffs = exclusive scan of rowcnt (local position of each segment)
    if (t < 256) sc[t] = rc;
    __syncthreads();
#pragma unroll
    for (int o = 1; o < 256; o <<= 1) {
        int u = (t < 256 && t >= o) ? sc[t - o] : 0;
        __syncthreads();
        if (t < 256) sc[t] += u;
        __syncthreads();
    }
    if (t < 256) boffs[t] = sc[t] - rc;
    if (t == 255) ssize = sc[255];
    __syncthreads();
    int base = sbase, size = ssize;

    // --- gather 196 segments into keys[] ---
    for (int jj = wid; jj < NBLK; jj += 8) {
        int len = rowcnt[jj];
        int gs  = jj * EPB + colpre[jj];
        int d0  = boffs[jj];
        for (int o = lane; o < len; o += 64) keys[d0 + o] = bket[gs + o];
    }
    if (t < 256) cnt[t] = 0;
    __syncthreads();

    // --- count per-dst ---
    for (int i = t; i < size; i += 512) atomicAdd(&cnt[(keys[i] >> 16) & 255], 1);
    __syncthreads();
    int cv = (t < 256) ? cnt[t] : 0;
    if (t < 256) sc[t] = cv;
    __syncthreads();
#pragma unroll
    for (int o = 1; o < 256; o <<= 1) {
        int u = (t < 256 && t >= o) ? sc[t - o] : 0;
        __syncthreads();
        if (t < 256) sc[t] += u;
        __syncthreads();
    }
    if (t < 256) { loc[t] = sc[t] - cv; fillb[t] = sc[t] - cv; }
    int node = b * 256 + t;
    if (t < 256 && node < N_NODES) {
        rowptr[node] = base + loc[t];
        dinv[node]   = rsqrtf((float)cv + 1.0f);   // + self-loop
    }
    if (b == 0 && t == 0) rowptr[N_NODES] = N_EDGES;
    __syncthreads();

    // --- rank-scatter in LDS, then coalesced write ---
    for (int i = t; i < size; i += 512) {
        unsigned int k = keys[i];
        int p = atomicAdd(&fillb[(k >> 16) & 255], 1);
        outb[p] = (unsigned short)(k & 0xFFFFu);
    }
    __syncthreads();
    for (int i = t; i < size; i += 512) ssrc[base + i] = outb[i];
}

// ============ GEMM1: h1s[N,64] = (x @ W1) * dinv, fp16 out ============

__global__ __launch_bounds__(256) void k_gemm1(const float* __restrict__ x,
                                               const float* __restrict__ W1,
                                               const float* __restrict__ dinv,
                                               __half* __restrict__ h1s) {
    __shared__ float sW[IN_F][HID_F];    // 32768 B
    __shared__ float sX[32][IN_F + 1];   // 16512 B
    int t = threadIdx.x;
    for (int i = t; i < IN_F * HID_F; i += 256)
        sW[i >> 6][i & 63] = W1[i];
    int row0 = blockIdx.x * 32;
    for (int i = t; i < 32 * 32; i += 256) {
        int r  = i >> 5;
        int c4 = i & 31;
        int gr = row0 + r;
        float4 v = make_float4(0.f, 0.f, 0.f, 0.f);
        if (gr < N_NODES) v = ((const float4*)x)[gr * 32 + c4];
        sX[r][c4 * 4 + 0] = v.x;
        sX[r][c4 * 4 + 1] = v.y;
        sX[r][c4 * 4 + 2] = v.z;
        sX[r][c4 * 4 + 3] = v.w;
    }
    __syncthreads();
    int c  = t & 63;
    int rg = t >> 6;
    float acc[8];
#pragma unroll
    for (int j = 0; j < 8; ++j) acc[j] = 0.f;
#pragma unroll 4
    for (int k = 0; k < IN_F; ++k) {
        float w = sW[k][c];
#pragma unroll
        for (int j = 0; j < 8; ++j)
            acc[j] += sX[rg * 8 + j][k] * w;
    }
#pragma unroll
    for (int j = 0; j < 8; ++j) {
        int gr = row0 + rg * 8 + j;
        if (gr < N_NODES) h1s[gr * HID_F + c] = __float2half(acc[j] * dinv[gr]);
    }
}

// ============ layer-1 aggregation + fused BN statistics ============
// grid is EXACTLY N_NODES/4 blocks -> every thread owns a valid node.

__global__ __launch_bounds__(256) void k_agg1(const int* __restrict__ rowptr,
                                              const unsigned short* __restrict__ ssrc,
                                              const float* __restrict__ dinv,
                                              const __half* __restrict__ h1s,
                                              const float* __restrict__ b1,
                                              __half* __restrict__ agg1h,
                                              float* __restrict__ st2) {
    int lane = threadIdx.x & 63;
    int rloc = threadIdx.x >> 6;
    int d = blockIdx.x * 4 + rloc;
    int base = rowptr[d];
    int end  = rowptr[d + 1];
    float acc = __half2float(h1s[d * HID_F + lane]);   // self-loop (pre-scaled)
    for (int j0 = base; j0 < end; j0 += 64) {
        int idx = j0 + lane;
        int sl = (idx < end) ? (int)ssrc[idx] : 0;
        int m = end - j0; if (m > 64) m = 64;
        for (int c0 = 0; c0 < m; c0 += 16) {
            float v[16];
#pragma unroll
            for (int k = 0; k < 16; ++k) {
                int j  = c0 + k;
                int jj = (j < m) ? j : (m - 1);      // wave-uniform clamp
                int s  = __shfl(sl, jj);
                v[k] = __half2float(h1s[s * HID_F + lane]);
            }
#pragma unroll
            for (int k = 0; k < 16; ++k)
                acc += (c0 + k < m) ? v[k] : 0.f;
        }
    }
    float val = acc * dinv[d] + b1[lane];
    agg1h[d * HID_F + lane] = __float2half(val);
    // BN partial sums: block-fold 4 rows, one replicated atomic pair per col
    __shared__ float ls[4][HID_F], ls2[4][HID_F];
    ls[rloc][lane]  = val;
    ls2[rloc][lane] = val * val;
    __syncthreads();
    if (rloc == 0) {
        float sm = ls[0][lane] + ls[1][lane] + ls[2][lane] + ls[3][lane];
        float s2 = ls2[0][lane] + ls2[1][lane] + ls2[2][lane] + ls2[3][lane];
        float* strow = st2 + (blockIdx.x & (NREP - 1)) * (2 * HID_F);
        atomicAdd(&strow[lane], sm);
        atomicAdd(&strow[HID_F + lane], s2);
    }
}

// ============ GEMM2 fused BN + ReLU, epilogue *dinv, fp16 in/out ============

__global__ __launch_bounds__(256) void k_gemm2(const __half* __restrict__ agg1h,
                                               const float* __restrict__ st2,
                                               const float* __restrict__ gamma,
                                               const float* __restrict__ beta,
                                               const float* __restrict__ W2,
                                               const float* __restrict__ dinv,
                                               __half* __restrict__ h2s) {
    __shared__ float sW[HID_F][OUT_F];
    __shared__ float sScale[HID_F], sShift[HID_F];
    int t = threadIdx.x;
    for (int i = t; i < HID_F * OUT_F; i += 256)
        sW[i / OUT_F][i % OUT_F] = W2[i];
    if (t < HID_F) {
        float sm = 0.f, s2 = 0.f;
#pragma unroll
        for (int r = 0; r < NREP; ++r) {
            sm += st2[r * (2 * HID_F) + t];
            s2 += st2[r * (2 * HID_F) + HID_F + t];
        }
        float mean = sm * (1.0f / N_NODES);
        float var  = s2 * (1.0f / N_NODES) - mean * mean;
        float inv  = rsqrtf(var + 1e-5f);
        float g    = gamma[t];
        sScale[t]  = g * inv;
        sShift[t]  = beta[t] - g * inv * mean;
    }
    __syncthreads();
    int row = blockIdx.x * 256 + t;
    if (row >= N_NODES) return;
    float acc[OUT_F];
#pragma unroll
    for (int c = 0; c < OUT_F; ++c) acc[c] = 0.f;
    const __half* arow = agg1h + (size_t)row * HID_F;
#pragma unroll 4
    for (int k = 0; k < HID_F; ++k) {
        float v = fmaxf(__half2float(arow[k]) * sScale[k] + sShift[k], 0.f);
#pragma unroll
        for (int c = 0; c < OUT_F; ++c) acc[c] += v * sW[k][c];
    }
    float di = dinv[row];
    __half* orow = h2s + (size_t)row * OUT_F;
#pragma unroll
    for (int c = 0; c < OUT_F; ++c) orow[c] = __float2half(acc[c] * di);
}

// ============ layer-2 aggregation: deep-MLP fp16 gather -> d_out ============

__global__ __launch_bounds__(256) void k_agg2(const int* __restrict__ rowptr,
                                              const unsigned short* __restrict__ ssrc,
                                              const float* __restrict__ dinv,
                                              const __half* __restrict__ h2s,
                                              const float* __restrict__ b2,
                                              float* __restrict__ out) {
    int lane = threadIdx.x & 63;
    int d = blockIdx.x * 4 + (threadIdx.x >> 6);
    int base = rowptr[d];
    int end  = rowptr[d + 1];
    int cl = (lane < OUT_F) ? lane : 0;
    float acc = __half2float(h2s[d * OUT_F + cl]);
    for (int j0 = base; j0 < end; j0 += 64) {
        int idx = j0 + lane;
        int sl = (idx < end) ? (int)ssrc[idx] : 0;
        int m = end - j0; if (m > 64) m = 64;
        for (int c0 = 0; c0 < m; c0 += 16) {
            float v[16];
#pragma unroll
            for (int k = 0; k < 16; ++k) {
                int j  = c0 + k;
                int jj = (j < m) ? j : (m - 1);
                int s  = __shfl(sl, jj);
                v[k] = __half2float(h2s[s * OUT_F + cl]);
            }
#pragma unroll
            for (int k = 0; k < 16; ++k)
                acc += (c0 + k < m) ? v[k] : 0.f;
        }
    }
    if (lane < OUT_F)
        out[d * OUT_F + lane] = acc * dinv[d] + b2[lane];
}

// ---------------- launch: 6 dispatches ----------------

extern "C" void kernel_launch(void* const* d_in, const int* in_sizes, int n_in,
                              void* d_out, int out_size, void* d_ws, size_t ws_size,
                              hipStream_t stream) {
    const float* x     = (const float*)d_in[0];
    const int*   ei    = (const int*)d_in[1];
    const float* W1    = (const float*)d_in[2];
    const float* b1    = (const float*)d_in[3];
    const float* gamma = (const float*)d_in[4];
    const float* beta  = (const float*)d_in[5];
    const float* W2    = (const float*)d_in[6];
    const float* b2    = (const float*)d_in[7];
    float* out = (float*)d_out;

    char* ws = (char*)d_ws;
    int*            blkcnt = (int*)           (ws + 0);          //   153,664 B
    int*            rowptr = (int*)           (ws + 154624);     //   200,004 B
    float*          dinv   = (float*)         (ws + 356352);     //   200,000 B
    float*          st2    = (float*)         (ws + 558080);     //    16,384 B
    unsigned int*   bket   = (unsigned int*)  (ws + 574464);     // 3,211,264 B
    unsigned short* ssrc   = (unsigned short*)(ws + 3785728);    // 1,600,000 B
    __half*         h1s    = (__half*)        (ws + 5387264);    // 6,400,000 B
    __half*         agg1h  = (__half*)        (ws + 11787264);   // 6,400,000 B
    __half*         h2s    = (__half*)        (ws + 18187264);   // 4,000,000 B
    // total ~22.2 MB

    k_binscatter<<<NBLK, 512, 0, stream>>>(ei, blkcnt, bket, st2);
    k_bucket<<<NBK, 512, 0, stream>>>(blkcnt, bket, rowptr, dinv, ssrc);
    k_gemm1<<<NB_G1, 256, 0, stream>>>(x, W1, dinv, h1s);
    k_agg1<<<N_NODES / 4, 256, 0, stream>>>(rowptr, ssrc, dinv, h1s, b1, agg1h, st2);
    k_gemm2<<<(N_NODES + 255) / 256, 256, 0, stream>>>(agg1h, st2, gamma, beta, W2, dinv, h2s);
    k_agg2<<<N_NODES / 4, 256, 0, stream>>>(rowptr, ssrc, dinv, h2s, b2, out);
}

// Round 8
// 209.725 us; speedup vs baseline: 2.6962x; 1.1092x over previous
//
#include <hip/hip_runtime.h>
#include <hip/hip_fp16.h>

#define N_NODES 50000
#define N_EDGES 800000
#define IN_F    128
#define HID_F   64
#define OUT_F   40

#define EPB   4096                          // edges per sort block
#define NBLK  ((N_EDGES + EPB - 1) / EPB)   // 196 sort blocks
#define NBK   ((N_NODES + 255) / 256)       // 196 buckets (dst >> 8)
#define CAP   6144                          // per-bucket LDS cap (avg 4082, sd 64)
#define NREP  32                            // BN-stat atomic replicas
#define NB_MM ((N_NODES + 63) / 64)         // 782 MFMA-GEMM blocks (64 rows each)

typedef _Float16 half8v __attribute__((ext_vector_type(8)));
typedef float    f32x4  __attribute__((ext_vector_type(4)));

// ============ pass 1: per-block bucket sort, block-local output ============

__global__ __launch_bounds__(512) void k_binscatter(const int* __restrict__ ei,
                                                    int* __restrict__ blkcnt,
                                                    unsigned int* __restrict__ bket,
                                                    float* __restrict__ st2) {
    __shared__ int h[256], fill[256], sc[256];
    __shared__ unsigned int staged[EPB];   // 16 KB
    int t = threadIdx.x;
    if (t < 256) h[t] = 0;
    if (blockIdx.x == 0)                   // zero BN-stat replicas once
        for (int i = t; i < NREP * 2 * HID_F; i += 512) st2[i] = 0.f;
    __syncthreads();
    int base = blockIdx.x * EPB;
    int nedge = N_EDGES - base; if (nedge > EPB) nedge = EPB;
#pragma unroll
    for (int it = 0; it < EPB / 512; ++it) {
        int e = base + it * 512 + t;
        if (e < N_EDGES) atomicAdd(&h[ei[N_EDGES + e] >> 8], 1);
    }
    __syncthreads();
    int v = (t < 256) ? h[t] : 0;
    if (t < 256) sc[t] = v;
    __syncthreads();
#pragma unroll
    for (int o = 1; o < 256; o <<= 1) {
        int u = (t < 256 && t >= o) ? sc[t - o] : 0;
        __syncthreads();
        if (t < 256) sc[t] += u;
        __syncthreads();
    }
    if (t < 256) fill[t] = sc[t] - v;      // exclusive
    __syncthreads();
#pragma unroll
    for (int it = 0; it < EPB / 512; ++it) {
        int e = base + it * 512 + t;
        if (e < N_EDGES) {
            int srcv = ei[e], dstv = ei[N_EDGES + e];
            int p = atomicAdd(&fill[dstv >> 8], 1);
            staged[p] = ((unsigned int)dstv << 16) | (unsigned int)srcv;
        }
    }
    __syncthreads();
    for (int i = t; i < nedge; i += 512) bket[base + i] = staged[i];   // coalesced
    if (t < NBK) blkcnt[t * NBLK + blockIdx.x] = h[t];
}

// ============ pass 2: per-bucket CSR build (scans done in-kernel) ============

__global__ __launch_bounds__(512) void k_bucket(const int* __restrict__ blkcnt,
                                                const unsigned int* __restrict__ bket,
                                                int* __restrict__ rowptr,
                                                float* __restrict__ dinv,
                                                unsigned short* __restrict__ ssrc) {
    __shared__ unsigned int keys[CAP];     // 24 KB
    __shared__ unsigned short outb[CAP];   // 12 KB
    __shared__ int colpre[256], rowcnt[256], boffs[256];
    __shared__ int cnt[256], loc[256], fillb[256], sc[256];
    __shared__ int wsum[8], sbase, ssize;
    int b = blockIdx.x, t = threadIdx.x;
    int lane = t & 63, wid = t >> 6;

    int cp = 0, rc = 0;
    if (t < NBLK) {
        for (int bp = 0; bp < b; ++bp) cp += blkcnt[bp * NBLK + t];   // coalesced
        rc = blkcnt[b * NBLK + t];
    }
    if (t < 256) { colpre[t] = cp; rowcnt[t] = rc; }
    int red = cp;
#pragma unroll
    for (int o = 32; o > 0; o >>= 1) red += __shfl_down(red, o);
    if (lane == 0) wsum[wid] = red;
    __syncthreads();
    if (t == 0) {
        int s = 0;
#pragma unroll
        for (int r = 0; r < 8; ++r) s += wsum[r];
        sbase = s;
    }
    if (t < 256) sc[t] = rc;
    __syncthreads();
#pragma unroll
    for (int o = 1; o < 256; o <<= 1) {
        int u = (t < 256 && t >= o) ? sc[t - o] : 0;
        __syncthreads();
        if (t < 256) sc[t] += u;
        __syncthreads();
    }
    if (t < 256) boffs[t] = sc[t] - rc;
    if (t == 255) ssize = sc[255];
    __syncthreads();
    int base = sbase, size = ssize;

    for (int jj = wid; jj < NBLK; jj += 8) {
        int len = rowcnt[jj];
        int gs  = jj * EPB + colpre[jj];
        int d0  = boffs[jj];
        for (int o = lane; o < len; o += 64) keys[d0 + o] = bket[gs + o];
    }
    if (t < 256) cnt[t] = 0;
    __syncthreads();

    for (int i = t; i < size; i += 512) atomicAdd(&cnt[(keys[i] >> 16) & 255], 1);
    __syncthreads();
    int cv = (t < 256) ? cnt[t] : 0;
    if (t < 256) sc[t] = cv;
    __syncthreads();
#pragma unroll
    for (int o = 1; o < 256; o <<= 1) {
        int u = (t < 256 && t >= o) ? sc[t - o] : 0;
        __syncthreads();
        if (t < 256) sc[t] += u;
        __syncthreads();
    }
    if (t < 256) { loc[t] = sc[t] - cv; fillb[t] = sc[t] - cv; }
    int node = b * 256 + t;
    if (t < 256 && node < N_NODES) {
        rowptr[node] = base + loc[t];
        dinv[node]   = rsqrtf((float)cv + 1.0f);   // + self-loop
    }
    if (b == 0 && t == 0) rowptr[N_NODES] = N_EDGES;
    __syncthreads();

    for (int i = t; i < size; i += 512) {
        unsigned int k = keys[i];
        int p = atomicAdd(&fillb[(k >> 16) & 255], 1);
        outb[p] = (unsigned short)(k & 0xFFFFu);
    }
    __syncthreads();
    for (int i = t; i < size; i += 512) ssrc[base + i] = outb[i];
}

// ============ GEMM1 (MFMA): h1s[N,64] = (x @ W1) * dinv, fp16 out ============
// 64 rows/block, v_mfma_f32_16x16x32_f16. A: x-tile fp16 in LDS (stride 136),
// B: W1^T fp16 in LDS. 4 waves x (4 ntiles x 4 ksteps) MFMA.

__global__ __launch_bounds__(256) void k_gemm1(const float* __restrict__ x,
                                               const float* __restrict__ W1,
                                               const float* __restrict__ dinv,
                                               __half* __restrict__ h1s) {
    __shared__ _Float16 sA[64][IN_F + 8];   // 17408 B
    __shared__ _Float16 sB[64][IN_F + 8];   // 17408 B  (sB[n][k] = W1[k][n])
    int t = threadIdx.x;
    int row0 = blockIdx.x * 64;
    // stage x tile: 64 rows x 32 float4
    for (int i = t; i < 64 * 32; i += 256) {
        int r  = i >> 5;
        int c4 = i & 31;
        int gr = row0 + r;
        float4 v = make_float4(0.f, 0.f, 0.f, 0.f);
        if (gr < N_NODES) v = ((const float4*)x)[gr * 32 + c4];
        sA[r][c4 * 4 + 0] = (_Float16)v.x;
        sA[r][c4 * 4 + 1] = (_Float16)v.y;
        sA[r][c4 * 4 + 2] = (_Float16)v.z;
        sA[r][c4 * 4 + 3] = (_Float16)v.w;
    }
    // stage W1 transposed: read coalesced over n, scatter to sB[n][k]
    for (int i = t; i < IN_F * HID_F; i += 256) {
        int k = i >> 6, n = i & 63;
        sB[n][k] = (_Float16)W1[i];
    }
    __syncthreads();

    int lane = t & 63, wid = t >> 6;
    int quad = lane >> 4, l15 = lane & 15;
    int m0 = wid * 16;
    // A-frags: one per kstep (reused across ntiles)
    half8v af[4];
#pragma unroll
    for (int ks = 0; ks < 4; ++ks)
        af[ks] = *(const half8v*)&sA[m0 + l15][ks * 32 + quad * 8];
    f32x4 acc[4];
#pragma unroll
    for (int nt = 0; nt < 4; ++nt) acc[nt] = (f32x4)(0.f);
#pragma unroll
    for (int nt = 0; nt < 4; ++nt) {
#pragma unroll
        for (int ks = 0; ks < 4; ++ks) {
            half8v bf = *(const half8v*)&sB[nt * 16 + l15][ks * 32 + quad * 8];
            acc[nt] = __builtin_amdgcn_mfma_f32_16x16x32_f16(af[ks], bf, acc[nt], 0, 0, 0);
        }
    }
    // epilogue: D row = m0 + quad*4 + reg, col = nt*16 + l15
    float dv[4];
    int rbase = row0 + m0 + quad * 4;
#pragma unroll
    for (int r = 0; r < 4; ++r)
        dv[r] = (rbase + r < N_NODES) ? dinv[rbase + r] : 0.f;
#pragma unroll
    for (int nt = 0; nt < 4; ++nt) {
        int col = nt * 16 + l15;
#pragma unroll
        for (int r = 0; r < 4; ++r) {
            int gr = rbase + r;
            if (gr < N_NODES)
                h1s[gr * HID_F + col] = __float2half(acc[nt][r] * dv[r]);
        }
    }
}

// ============ layer-1 aggregation + fused BN statistics ============

__global__ __launch_bounds__(256) void k_agg1(const int* __restrict__ rowptr,
                                              const unsigned short* __restrict__ ssrc,
                                              const float* __restrict__ dinv,
                                              const __half* __restrict__ h1s,
                                              const float* __restrict__ b1,
                                              __half* __restrict__ agg1h,
                                              float* __restrict__ st2) {
    int lane = threadIdx.x & 63;
    int rloc = threadIdx.x >> 6;
    int d = blockIdx.x * 4 + rloc;
    int base = rowptr[d];
    int end  = rowptr[d + 1];
    float acc = __half2float(h1s[d * HID_F + lane]);   // self-loop (pre-scaled)
    for (int j0 = base; j0 < end; j0 += 64) {
        int idx = j0 + lane;
        int sl = (idx < end) ? (int)ssrc[idx] : 0;
        int m = end - j0; if (m > 64) m = 64;
        for (int c0 = 0; c0 < m; c0 += 16) {
            float v[16];
#pragma unroll
            for (int k = 0; k < 16; ++k) {
                int j  = c0 + k;
                int jj = (j < m) ? j : (m - 1);      // wave-uniform clamp
                int s  = __shfl(sl, jj);
                v[k] = __half2float(h1s[s * HID_F + lane]);
            }
#pragma unroll
            for (int k = 0; k < 16; ++k)
                acc += (c0 + k < m) ? v[k] : 0.f;
        }
    }
    float val = acc * dinv[d] + b1[lane];
    agg1h[d * HID_F + lane] = __float2half(val);
    __shared__ float ls[4][HID_F], ls2[4][HID_F];
    ls[rloc][lane]  = val;
    ls2[rloc][lane] = val * val;
    __syncthreads();
    if (rloc == 0) {
        float sm = ls[0][lane] + ls[1][lane] + ls[2][lane] + ls[3][lane];
        float s2 = ls2[0][lane] + ls2[1][lane] + ls2[2][lane] + ls2[3][lane];
        float* strow = st2 + (blockIdx.x & (NREP - 1)) * (2 * HID_F);
        atomicAdd(&strow[lane], sm);
        atomicAdd(&strow[HID_F + lane], s2);
    }
}

// ============ GEMM2 (MFMA): h2s = relu(bn(agg1)) @ W2 * dinv, fp16 ============
// 64 rows/block. BN+ReLU applied during staging. N padded 40->48.

__global__ __launch_bounds__(256) void k_gemm2(const __half* __restrict__ agg1h,
                                               const float* __restrict__ st2,
                                               const float* __restrict__ gamma,
                                               const float* __restrict__ beta,
                                               const float* __restrict__ W2,
                                               const float* __restrict__ dinv,
                                               __half* __restrict__ h2s) {
    __shared__ _Float16 sA[64][HID_F + 8];   // 9216 B
    __shared__ _Float16 sB[48][HID_F + 8];   // 6912 B  (sB[n][k] = W2[k][n], pad n>=40)
    __shared__ float sScale[HID_F], sShift[HID_F];
    int t = threadIdx.x;
    if (t < HID_F) {
        float sm = 0.f, s2 = 0.f;
#pragma unroll
        for (int r = 0; r < NREP; ++r) {
            sm += st2[r * (2 * HID_F) + t];
            s2 += st2[r * (2 * HID_F) + HID_F + t];
        }
        float mean = sm * (1.0f / N_NODES);
        float var  = s2 * (1.0f / N_NODES) - mean * mean;
        float inv  = rsqrtf(var + 1e-5f);
        float g    = gamma[t];
        sScale[t]  = g * inv;
        sShift[t]  = beta[t] - g * inv * mean;
    }
    // stage W2^T (read coalesced over n)
    for (int i = t; i < 48 * HID_F; i += 256) {
        int k = i / 48, n = i - k * 48;
        sB[n][k] = (n < OUT_F) ? (_Float16)W2[k * OUT_F + n] : (_Float16)0.f;
    }
    __syncthreads();   // sScale ready before staging uses it
    int row0 = blockIdx.x * 64;
    for (int i = t; i < 64 * HID_F; i += 256) {
        int r = i >> 6, k = i & 63;
        int gr = row0 + r;
        float v = 0.f;
        if (gr < N_NODES) {
            float a = __half2float(agg1h[gr * HID_F + k]);
            v = fmaxf(a * sScale[k] + sShift[k], 0.f);
        }
        sA[r][k] = (_Float16)v;
    }
    __syncthreads();

    int lane = t & 63, wid = t >> 6;
    int quad = lane >> 4, l15 = lane & 15;
    int m0 = wid * 16;
    half8v af[2];
#pragma unroll
    for (int ks = 0; ks < 2; ++ks)
        af[ks] = *(const half8v*)&sA[m0 + l15][ks * 32 + quad * 8];
    f32x4 acc[3];
#pragma unroll
    for (int nt = 0; nt < 3; ++nt) acc[nt] = (f32x4)(0.f);
#pragma unroll
    for (int nt = 0; nt < 3; ++nt) {
#pragma unroll
        for (int ks = 0; ks < 2; ++ks) {
            half8v bf = *(const half8v*)&sB[nt * 16 + l15][ks * 32 + quad * 8];
            acc[nt] = __builtin_amdgcn_mfma_f32_16x16x32_f16(af[ks], bf, acc[nt], 0, 0, 0);
        }
    }
    float dv[4];
    int rbase = row0 + m0 + quad * 4;
#pragma unroll
    for (int r = 0; r < 4; ++r)
        dv[r] = (rbase + r < N_NODES) ? dinv[rbase + r] : 0.f;
#pragma unroll
    for (int nt = 0; nt < 3; ++nt) {
        int col = nt * 16 + l15;
        if (col < OUT_F) {
#pragma unroll
            for (int r = 0; r < 4; ++r) {
                int gr = rbase + r;
                if (gr < N_NODES)
                    h2s[gr * OUT_F + col] = __float2half(acc[nt][r] * dv[r]);
            }
        }
    }
}

// ============ layer-2 aggregation: deep-MLP fp16 gather -> d_out ============

__global__ __launch_bounds__(256) void k_agg2(const int* __restrict__ rowptr,
                                              const unsigned short* __restrict__ ssrc,
                                              const float* __restrict__ dinv,
                                              const __half* __restrict__ h2s,
                                              const float* __restrict__ b2,
                                              float* __restrict__ out) {
    int lane = threadIdx.x & 63;
    int d = blockIdx.x * 4 + (threadIdx.x >> 6);
    int base = rowptr[d];
    int end  = rowptr[d + 1];
    int cl = (lane < OUT_F) ? lane : 0;
    float acc = __half2float(h2s[d * OUT_F + cl]);
    for (int j0 = base; j0 < end; j0 += 64) {
        int idx = j0 + lane;
        int sl = (idx < end) ? (int)ssrc[idx] : 0;
        int m = end - j0; if (m > 64) m = 64;
        for (int c0 = 0; c0 < m; c0 += 16) {
            float v[16];
#pragma unroll
            for (int k = 0; k < 16; ++k) {
                int j  = c0 + k;
                int jj = (j < m) ? j : (m - 1);
                int s  = __shfl(sl, jj);
                v[k] = __half2float(h2s[s * OUT_F + cl]);
            }
#pragma unroll
            for (int k = 0; k < 16; ++k)
                acc += (c0 + k < m) ? v[k] : 0.f;
        }
    }
    if (lane < OUT_F)
        out[d * OUT_F + lane] = acc * dinv[d] + b2[lane];
}

// ---------------- launch: 6 dispatches ----------------

extern "C" void kernel_launch(void* const* d_in, const int* in_sizes, int n_in,
                              void* d_out, int out_size, void* d_ws, size_t ws_size,
                              hipStream_t stream) {
    const float* x     = (const float*)d_in[0];
    const int*   ei    = (const int*)d_in[1];
    const float* W1    = (const float*)d_in[2];
    const float* b1    = (const float*)d_in[3];
    const float* gamma = (const float*)d_in[4];
    const float* beta  = (const float*)d_in[5];
    const float* W2    = (const float*)d_in[6];
    const float* b2    = (const float*)d_in[7];
    float* out = (float*)d_out;

    char* ws = (char*)d_ws;
    int*            blkcnt = (int*)           (ws + 0);          //   153,664 B
    int*            rowptr = (int*)           (ws + 154624);     //   200,004 B
    float*          dinv   = (float*)         (ws + 356352);     //   200,000 B
    float*          st2    = (float*)         (ws + 558080);     //    16,384 B
    unsigned int*   bket   = (unsigned int*)  (ws + 574464);     // 3,211,264 B
    unsigned short* ssrc   = (unsigned short*)(ws + 3785728);    // 1,600,000 B
    __half*         h1s    = (__half*)        (ws + 5387264);    // 6,400,000 B
    __half*         agg1h  = (__half*)        (ws + 11787264);   // 6,400,000 B
    __half*         h2s    = (__half*)        (ws + 18187264);   // 4,000,000 B
    // total ~22.2 MB

    k_binscatter<<<NBLK, 512, 0, stream>>>(ei, blkcnt, bket, st2);
    k_bucket<<<NBK, 512, 0, stream>>>(blkcnt, bket, rowptr, dinv, ssrc);
    k_gemm1<<<NB_MM, 256, 0, stream>>>(x, W1, dinv, h1s);
    k_agg1<<<N_NODES / 4, 256, 0, stream>>>(rowptr, ssrc, dinv, h1s, b1, agg1h, st2);
    k_gemm2<<<NB_MM, 256, 0, stream>>>(agg1h, st2, gamma, beta, W2, dinv, h2s);
    k_agg2<<<N_NODES / 4, 256, 0, stream>>>(rowptr, ssrc, dinv, h2s, b2, out);
}